// Round 1
// baseline (10777.133 us; speedup 1.0000x reference)
//
#include <hip/hip_runtime.h>
#include <math.h>

#define NN 20000
#define FIN 256
#define HIDDIM 256
#define EMB 128
#define HEADS 8
#define GDIM (HEADS*EMB)   // 1024

// ---------- helpers ----------
__device__ __forceinline__ float lrelu(float x){ return x > 0.f ? x : 0.2f*x; }
// order-preserving float<->uint for atomicMax on floats
__device__ __forceinline__ unsigned ordU(float f){
    unsigned u = __float_as_uint(f);
    return (u & 0x80000000u) ? ~u : (u | 0x80000000u);
}
__device__ __forceinline__ float unordU(unsigned u){
    return (u & 0x80000000u) ? __uint_as_float(u & 0x7fffffffu) : __uint_as_float(~u);
}

// ---------- degree / dinv ----------
__global__ __launch_bounds__(256) void deg_init_k(float* __restrict__ deg){
    int i = blockIdx.x*256 + threadIdx.x;
    if (i < NN) deg[i] = 1.f;           // self loop
}
__global__ __launch_bounds__(256) void deg_edge_k(const int* __restrict__ dst, float* __restrict__ deg, int E){
    int i = blockIdx.x*256 + threadIdx.x;
    if (i < E) unsafeAtomicAdd(&deg[dst[i]], 1.f);
}
__global__ __launch_bounds__(256) void dinv_k(float* __restrict__ deg){
    int i = blockIdx.x*256 + threadIdx.x;
    if (i < NN) deg[i] = 1.f / sqrtf(deg[i]);
}

// ---------- fp32 GEMM: C[M,N] = A[M,K] @ B[K,N]  (+abias on A cols, +bias, relu) ----------
template<bool RELU, bool HAS_BIAS, bool ADD_ABIAS>
__global__ __launch_bounds__(256,2) void gemm_k(const float* __restrict__ A, const float* __restrict__ B,
        const float* __restrict__ bias, const float* __restrict__ abias, float* __restrict__ C,
        int M, int N, int K)
{
    const int BM=128, BN=128, BK=16;
    __shared__ float As[BK][BM+4];
    __shared__ float Bs[BK][BN];
    int tid = threadIdx.x;
    int tx = tid & 15;
    int ty = tid >> 4;
    int m0 = blockIdx.y * BM, n0 = blockIdx.x * BN;
    float acc[8][8] = {};
    for (int k0 = 0; k0 < K; k0 += BK){
        #pragma unroll
        for (int q = 0; q < 2; ++q){
            int idx = tid*2 + q;
            int arow = idx >> 2, ak = (idx & 3)*4;
            float4 av = {0.f,0.f,0.f,0.f};
            int am = m0 + arow;
            if (am < M) av = *(const float4*)(A + (size_t)am*K + k0 + ak);
            if (ADD_ABIAS){
                av.x += abias[k0+ak+0]; av.y += abias[k0+ak+1];
                av.z += abias[k0+ak+2]; av.w += abias[k0+ak+3];
            }
            As[ak+0][arow]=av.x; As[ak+1][arow]=av.y; As[ak+2][arow]=av.z; As[ak+3][arow]=av.w;
            int brow = idx >> 5, bc = (idx & 31)*4;
            float4 bv = *(const float4*)(B + (size_t)(k0+brow)*N + n0 + bc);
            *(float4*)&Bs[brow][bc] = bv;
        }
        __syncthreads();
        #pragma unroll
        for (int kk = 0; kk < BK; ++kk){
            float a[8], b[8];
            *(float4*)&a[0] = *(const float4*)&As[kk][ty*8];
            *(float4*)&a[4] = *(const float4*)&As[kk][ty*8+4];
            *(float4*)&b[0] = *(const float4*)&Bs[kk][tx*8];
            *(float4*)&b[4] = *(const float4*)&Bs[kk][tx*8+4];
            #pragma unroll
            for (int i=0;i<8;++i)
                #pragma unroll
                for (int j=0;j<8;++j) acc[i][j] = fmaf(a[i], b[j], acc[i][j]);
        }
        __syncthreads();
    }
    #pragma unroll
    for (int i=0;i<8;++i){
        int m = m0 + ty*8 + i;
        if (m >= M) continue;
        #pragma unroll
        for (int j=0;j<8;j+=4){
            int n = n0 + tx*8 + j;
            float4 v; v.x=acc[i][j]; v.y=acc[i][j+1]; v.z=acc[i][j+2]; v.w=acc[i][j+3];
            if (HAS_BIAS){ v.x+=bias[n]; v.y+=bias[n+1]; v.z+=bias[n+2]; v.w+=bias[n+3]; }
            if (RELU){ v.x=fmaxf(v.x,0.f); v.y=fmaxf(v.y,0.f); v.z=fmaxf(v.z,0.f); v.w=fmaxf(v.w,0.f); }
            *(float4*)(C + (size_t)m*N + n) = v;
        }
    }
}

// ---------- GCN aggregation ----------
template<int F>
__global__ __launch_bounds__(256) void gcn_self_k(const float* __restrict__ h, const float* __restrict__ dinv,
                                                  float* __restrict__ agg){
    int i = blockIdx.x*256 + threadIdx.x;    // over NN*F (divisible by 256)
    int node = i / F;
    float di = dinv[node];
    agg[i] = h[i]*di*di;
}
template<int F>
__global__ __launch_bounds__(256) void gcn_edge_k(const float* __restrict__ h, const int* __restrict__ src,
        const int* __restrict__ dst, const float* __restrict__ dinv, float* __restrict__ agg, int E){
    int wv = (blockIdx.x*256 + threadIdx.x) >> 6;
    int lane = threadIdx.x & 63;
    if (wv >= E) return;
    int s = src[wv], d = dst[wv];
    float coef = dinv[s]*dinv[d];
    if (F == 256){
        float4 v = *(const float4*)(h + (size_t)s*F + lane*4);
        float* p = agg + (size_t)d*F + lane*4;
        unsafeAtomicAdd(p+0, v.x*coef); unsafeAtomicAdd(p+1, v.y*coef);
        unsafeAtomicAdd(p+2, v.z*coef); unsafeAtomicAdd(p+3, v.w*coef);
    } else {
        float2 v = *(const float2*)(h + (size_t)s*F + lane*2);
        float* p = agg + (size_t)d*F + lane*2;
        unsafeAtomicAdd(p+0, v.x*coef); unsafeAtomicAdd(p+1, v.y*coef);
    }
}
template<int F>
__global__ __launch_bounds__(256) void bias_relu_k(const float* __restrict__ agg, const float* __restrict__ b,
                                                   float* __restrict__ out){
    int i = blockIdx.x*256 + threadIdx.x;
    out[i] = fmaxf(agg[i] + b[i & (F-1)], 0.f);
}

// ---------- GAT ----------
__global__ __launch_bounds__(256) void gat_dots_k(const float* __restrict__ hg, const float* __restrict__ att_src,
        const float* __restrict__ att_dst, float* __restrict__ a_s, float* __restrict__ a_d){
    int wv = (blockIdx.x*256 + threadIdx.x) >> 6;   // over NN*HEADS
    int lane = threadIdx.x & 63;
    if (wv >= NN*HEADS) return;
    int n = wv >> 3, h = wv & 7;
    const float* row = hg + (size_t)n*GDIM + h*EMB;
    float2 v  = *(const float2*)(row + lane*2);
    float2 s2 = *(const float2*)(att_src + h*EMB + lane*2);
    float2 d2 = *(const float2*)(att_dst + h*EMB + lane*2);
    float ss = v.x*s2.x + v.y*s2.y;
    float sd = v.x*d2.x + v.y*d2.y;
    #pragma unroll
    for (int off=32; off; off>>=1){ ss += __shfl_down(ss, off, 64); sd += __shfl_down(sd, off, 64); }
    if (!lane){ a_s[wv] = ss; a_d[wv] = sd; }
}
__global__ __launch_bounds__(256) void gat_minit_k(const float* __restrict__ a_s, const float* __restrict__ a_d,
                                                   unsigned* __restrict__ mord){
    int i = blockIdx.x*256 + threadIdx.x;     // NN*8 divisible by 256
    float e = lrelu(a_s[i] + a_d[i]);         // self loop
    mord[i] = ordU(e);
}
__global__ __launch_bounds__(256) void gat_emax_k(const int* __restrict__ src, const int* __restrict__ dst,
        const float* __restrict__ a_s, const float* __restrict__ a_d, unsigned* __restrict__ mord, int E){
    int t = blockIdx.x*256 + threadIdx.x;     // over E*8
    if (t >= E*HEADS) return;
    int e = t >> 3, h = t & 7;
    int s = src[e], d = dst[e];
    float ev = lrelu(a_s[s*HEADS+h] + a_d[d*HEADS+h]);
    atomicMax(&mord[d*HEADS+h], ordU(ev));
}
__global__ __launch_bounds__(256) void gat_node1_k(const float* __restrict__ a_s, const float* __restrict__ a_d,
        const unsigned* __restrict__ mord, float* __restrict__ m, float* __restrict__ denom){
    int i = blockIdx.x*256 + threadIdx.x;
    float mv = unordU(mord[i]);
    m[i] = mv;
    float es = lrelu(a_s[i] + a_d[i]);
    denom[i] = expf(es - mv);                 // self-loop term
}
__global__ __launch_bounds__(256) void gat_eex_k(const int* __restrict__ src, const int* __restrict__ dst,
        const float* __restrict__ a_s, const float* __restrict__ a_d, const float* __restrict__ m,
        float* __restrict__ ex, float* __restrict__ denom, int E){
    int t = blockIdx.x*256 + threadIdx.x;
    if (t >= E*HEADS) return;
    int e = t >> 3, h = t & 7;
    int s = src[e], d = dst[e];
    float ev = lrelu(a_s[s*HEADS+h] + a_d[d*HEADS+h]);
    float x = expf(ev - m[d*HEADS+h]);
    ex[t] = x;
    unsafeAtomicAdd(&denom[d*HEADS+h], x);
}
__global__ __launch_bounds__(256) void gat_selfout_k(const float* __restrict__ hg, const float* __restrict__ a_s,
        const float* __restrict__ a_d, const float* __restrict__ m, const float* __restrict__ denom,
        float* __restrict__ gat){
    int i = blockIdx.x*256 + threadIdx.x;     // over NN*1024
    int n = i >> 10, h = (i >> 7) & 7;
    int nh = n*HEADS + h;
    float es = lrelu(a_s[nh] + a_d[nh]);
    float alpha = expf(es - m[nh]) / denom[nh];
    gat[i] = hg[i] * alpha;
}
__global__ __launch_bounds__(256) void gat_escatter_k(const int* __restrict__ src, const int* __restrict__ dst,
        const float* __restrict__ hg, const float* __restrict__ ex, const float* __restrict__ denom,
        float* __restrict__ gat, int E){
    int wv = (blockIdx.x*256 + threadIdx.x) >> 6;
    int lane = threadIdx.x & 63;
    if (wv >= E) return;
    int s = src[wv], d = dst[wv];
    int h = lane >> 3;                        // 16 floats/lane → one head per lane
    float alpha = ex[(size_t)wv*HEADS + h] / denom[d*HEADS + h];
    const float* hrow = hg  + (size_t)s*GDIM + lane*16;
    float*       orow = gat + (size_t)d*GDIM + lane*16;
    #pragma unroll
    for (int q = 0; q < 4; ++q){
        float4 v = *(const float4*)(hrow + q*4);
        unsafeAtomicAdd(orow + q*4 + 0, v.x*alpha);
        unsafeAtomicAdd(orow + q*4 + 1, v.y*alpha);
        unsafeAtomicAdd(orow + q*4 + 2, v.z*alpha);
        unsafeAtomicAdd(orow + q*4 + 3, v.w*alpha);
    }
}

// ---------- head: logits -> sigmoid ----------
__global__ __launch_bounds__(256) void head_k(const float* __restrict__ z, const float* __restrict__ Wh2,
        const float* __restrict__ bh2, float* __restrict__ w){
    int wv = (blockIdx.x*256 + threadIdx.x) >> 6;
    int lane = threadIdx.x & 63;
    if (wv >= NN) return;
    float4 zv = *(const float4*)(z + (size_t)wv*HIDDIM + lane*4);
    float4 wv4 = *(const float4*)(Wh2 + lane*4);
    float s = zv.x*wv4.x + zv.y*wv4.y + zv.z*wv4.z + zv.w*wv4.w;
    #pragma unroll
    for (int off=32; off; off>>=1) s += __shfl_down(s, off, 64);
    if (!lane){
        float logit = s + bh2[0];
        w[wv] = 1.f / (1.f + expf(-logit));
    }
}

// ---------- global softmax ----------
__global__ void red_init_k(float* red){
    if (threadIdx.x == 0){ ((unsigned*)red)[0] = 0u; red[1] = 0.f; }
}
__global__ __launch_bounds__(256) void red_max_k(const float* __restrict__ w, float* __restrict__ red){
    __shared__ float s[256];
    float v = 0.f;    // sigmoid > 0
    for (int i = blockIdx.x*256 + threadIdx.x; i < NN; i += gridDim.x*256) v = fmaxf(v, w[i]);
    s[threadIdx.x] = v; __syncthreads();
    for (int off=128; off; off>>=1){
        if (threadIdx.x < off) s[threadIdx.x] = fmaxf(s[threadIdx.x], s[threadIdx.x+off]);
        __syncthreads();
    }
    if (!threadIdx.x) atomicMax((unsigned*)red, ordU(s[0]));
}
__global__ __launch_bounds__(256) void red_sum_k(const float* __restrict__ w, float* __restrict__ red){
    float mx = unordU(((const unsigned*)red)[0]);
    __shared__ float s[256];
    float v = 0.f;
    for (int i = blockIdx.x*256 + threadIdx.x; i < NN; i += gridDim.x*256) v += expf(w[i]-mx);
    s[threadIdx.x] = v; __syncthreads();
    for (int off=128; off; off>>=1){
        if (threadIdx.x < off) s[threadIdx.x] += s[threadIdx.x+off];
        __syncthreads();
    }
    if (!threadIdx.x) unsafeAtomicAdd(&red[1], s[0]);
}
__global__ __launch_bounds__(256) void final_k(const float* __restrict__ w, const float* __restrict__ red,
                                               float* __restrict__ out){
    int i = blockIdx.x*256 + threadIdx.x;
    if (i >= NN) return;
    float mx = unordU(((const unsigned*)red)[0]);
    out[i] = expf(w[i]-mx) / red[1];
}

// ---------- launch ----------
extern "C" void kernel_launch(void* const* d_in, const int* in_sizes, int n_in,
                              void* d_out, int out_size, void* d_ws, size_t ws_size,
                              hipStream_t stream) {
    const float* x   = (const float*)d_in[0];
    const int*   ei  = (const int*)  d_in[1];
    const float* W1  = (const float*)d_in[2];
    const float* b1  = (const float*)d_in[3];
    const float* W2  = (const float*)d_in[4];
    const float* b2  = (const float*)d_in[5];
    const float* W3  = (const float*)d_in[6];
    const float* b3  = (const float*)d_in[7];
    const float* Wg  = (const float*)d_in[8];
    const float* att_src = (const float*)d_in[9];
    const float* att_dst = (const float*)d_in[10];
    const float* bg  = (const float*)d_in[11];
    const float* Wh1 = (const float*)d_in[12];
    const float* bh1 = (const float*)d_in[13];
    const float* Wh2 = (const float*)d_in[14];
    const float* bh2 = (const float*)d_in[15];
    float* out = (float*)d_out;

    const int E = in_sizes[1] / 2;
    const int* src = ei;
    const int* dst = ei + E;

    float* ws = (float*)d_ws;
    size_t o = 0;
    auto alloc = [&](size_t n){ float* p = ws + o; o += n; return p; };
    float* dinv  = alloc(NN);
    float* bufA  = alloc((size_t)NN*HIDDIM);
    float* bufB  = alloc((size_t)NN*HIDDIM);
    float* hg    = alloc((size_t)NN*GDIM);
    float* gat   = alloc((size_t)NN*GDIM);
    float* a_s   = alloc((size_t)NN*HEADS);
    float* a_d   = alloc((size_t)NN*HEADS);
    float* m_    = alloc((size_t)NN*HEADS);
    float* denom = alloc((size_t)NN*HEADS);
    unsigned* mord = (unsigned*)alloc((size_t)NN*HEADS);
    float* ex    = alloc((size_t)E*HEADS);
    float* wsig  = alloc(NN);
    float* red   = alloc(8);

    const int nb  = (NN + 255)/256;
    const int eb  = (E + 255)/256;
    const int ewb = (E + 3)/4;          // 1 wave/edge, 4 waves/block
    const int nhb = (NN*HEADS)/256;
    const int ehb = (E*HEADS + 255)/256;
    const dim3 blk(256);

    // degrees
    deg_init_k<<<nb, blk, 0, stream>>>(dinv);
    deg_edge_k<<<eb, blk, 0, stream>>>(dst, dinv, E);
    dinv_k<<<nb, blk, 0, stream>>>(dinv);

    const int MT = (NN + 127)/128;      // 157

    // GCN layer 1 (K=256,N=256)
    gemm_k<false,false,false><<<dim3(2, MT), blk, 0, stream>>>(x, W1, nullptr, nullptr, bufA, NN, 256, 256);
    gcn_self_k<256><<<(NN*256)/256, blk, 0, stream>>>(bufA, dinv, bufB);
    gcn_edge_k<256><<<ewb, blk, 0, stream>>>(bufA, src, dst, dinv, bufB, E);
    bias_relu_k<256><<<(NN*256)/256, blk, 0, stream>>>(bufB, b1, bufA);

    // GCN layer 2
    gemm_k<false,false,false><<<dim3(2, MT), blk, 0, stream>>>(bufA, W2, nullptr, nullptr, bufB, NN, 256, 256);
    gcn_self_k<256><<<(NN*256)/256, blk, 0, stream>>>(bufB, dinv, bufA);
    gcn_edge_k<256><<<ewb, blk, 0, stream>>>(bufB, src, dst, dinv, bufA, E);
    bias_relu_k<256><<<(NN*256)/256, blk, 0, stream>>>(bufA, b2, bufB);

    // GCN layer 3 (K=256,N=128)
    gemm_k<false,false,false><<<dim3(1, MT), blk, 0, stream>>>(bufB, W3, nullptr, nullptr, bufA, NN, 128, 256);
    gcn_self_k<128><<<(NN*128)/256, blk, 0, stream>>>(bufA, dinv, bufB);
    gcn_edge_k<128><<<ewb, blk, 0, stream>>>(bufA, src, dst, dinv, bufB, E);
    bias_relu_k<128><<<(NN*128)/256, blk, 0, stream>>>(bufB, b3, bufA);

    // GAT projection (K=128,N=1024)
    gemm_k<false,false,false><<<dim3(8, MT), blk, 0, stream>>>(bufA, Wg, nullptr, nullptr, hg, NN, 1024, 128);
    gat_dots_k<<<(NN*HEADS)/4, blk, 0, stream>>>(hg, att_src, att_dst, a_s, a_d);
    gat_minit_k<<<nhb, blk, 0, stream>>>(a_s, a_d, mord);
    gat_emax_k<<<ehb, blk, 0, stream>>>(src, dst, a_s, a_d, mord, E);
    gat_node1_k<<<nhb, blk, 0, stream>>>(a_s, a_d, mord, m_, denom);
    gat_eex_k<<<ehb, blk, 0, stream>>>(src, dst, a_s, a_d, m_, ex, denom, E);
    gat_selfout_k<<<(NN*GDIM)/256, blk, 0, stream>>>(hg, a_s, a_d, m_, denom, gat);
    gat_escatter_k<<<ewb, blk, 0, stream>>>(src, dst, hg, ex, denom, gat, E);

    // head MLP (K=1024,N=256) with fused +bg on A and relu+bh1 on out
    gemm_k<true,true,true><<<dim3(2, MT), blk, 0, stream>>>(gat, Wh1, bh1, bg, bufA, NN, 256, 1024);
    head_k<<<(NN + 3)/4, blk, 0, stream>>>(bufA, Wh2, bh2, wsig);

    // global softmax over sigmoid(logits)
    red_init_k<<<1, 64, 0, stream>>>(red);
    red_max_k<<<40, blk, 0, stream>>>(wsig, red);
    red_sum_k<<<40, blk, 0, stream>>>(wsig, red);
    final_k<<<nb, blk, 0, stream>>>(wsig, red, out);
}

// Round 2
// 782.684 us; speedup vs baseline: 13.7695x; 13.7695x over previous
//
#include <hip/hip_runtime.h>
#include <math.h>

#define NN 20000
#define HIDDIM 256
#define EMB 128
#define HEADS 8
#define GDIM (HEADS*EMB)   // 1024

// ---------- helpers ----------
__device__ __forceinline__ float lrelu(float x){ return x > 0.f ? x : 0.2f*x; }
__device__ __forceinline__ unsigned ordU(float f){
    unsigned u = __float_as_uint(f);
    return (u & 0x80000000u) ? ~u : (u | 0x80000000u);
}
__device__ __forceinline__ float unordU(unsigned u){
    return (u & 0x80000000u) ? __uint_as_float(u & 0x7fffffffu) : __uint_as_float(~u);
}

// ---------- CSR build ----------
__global__ __launch_bounds__(256) void zero_int_k(int* __restrict__ p, int n){
    int i = blockIdx.x*256 + threadIdx.x;
    if (i < n) p[i] = 0;
}
__global__ __launch_bounds__(256) void hist_k(const int* __restrict__ dst, int* __restrict__ cnt, int E){
    int i = blockIdx.x*256 + threadIdx.x;
    if (i < E) atomicAdd(&cnt[dst[i]], 1);
}
// single-block exclusive scan of cnt[0..NN) -> row_off[0..NN]
__global__ __launch_bounds__(1024) void scan_k(const int* __restrict__ cnt, int* __restrict__ row_off){
    __shared__ int tot[1024];
    int t = threadIdx.x;
    const int CH = 20;                     // 1024*20 >= 20000
    int base = t*CH;
    int loc[CH]; int s = 0;
    #pragma unroll
    for (int i = 0; i < CH; ++i){
        int v = (base+i < NN) ? cnt[base+i] : 0;
        loc[i] = s; s += v;
    }
    tot[t] = s; __syncthreads();
    for (int off = 1; off < 1024; off <<= 1){
        int v = (t >= off) ? tot[t-off] : 0;
        __syncthreads();
        tot[t] += v;
        __syncthreads();
    }
    int pre = (t == 0) ? 0 : tot[t-1];
    #pragma unroll
    for (int i = 0; i < CH; ++i)
        if (base+i < NN) row_off[base+i] = pre + loc[i];
    if (t == 1023) row_off[NN] = tot[1023];
}
__global__ __launch_bounds__(256) void dinv_k(const int* __restrict__ cnt, float* __restrict__ dinv){
    int i = blockIdx.x*256 + threadIdx.x;
    if (i < NN) dinv[i] = rsqrtf((float)cnt[i] + 1.f);   // +1 self loop
}
__global__ __launch_bounds__(256) void scatter_k(const int* __restrict__ src, const int* __restrict__ dst,
        const int* __restrict__ row_off, int* __restrict__ cursor, int* __restrict__ src_sorted, int E){
    int i = blockIdx.x*256 + threadIdx.x;
    if (i >= E) return;
    int d = dst[i];
    int pos = row_off[d] + atomicAdd(&cursor[d], 1);
    src_sorted[pos] = src[i];
}

// ---------- fp32 GEMM: C[M,N] = A[M,K] @ B[K,N]  (+abias on A cols, +bias, relu) ----------
template<bool RELU, bool HAS_BIAS, bool ADD_ABIAS>
__global__ __launch_bounds__(256,2) void gemm_k(const float* __restrict__ A, const float* __restrict__ B,
        const float* __restrict__ bias, const float* __restrict__ abias, float* __restrict__ C,
        int M, int N, int K)
{
    const int BM=128, BN=128, BK=16;
    __shared__ float As[BK][BM+4];
    __shared__ float Bs[BK][BN];
    int tid = threadIdx.x;
    int tx = tid & 15;
    int ty = tid >> 4;
    int m0 = blockIdx.y * BM, n0 = blockIdx.x * BN;
    float acc[8][8] = {};
    for (int k0 = 0; k0 < K; k0 += BK){
        #pragma unroll
        for (int q = 0; q < 2; ++q){
            int idx = tid*2 + q;
            int arow = idx >> 2, ak = (idx & 3)*4;
            float4 av = {0.f,0.f,0.f,0.f};
            int am = m0 + arow;
            if (am < M) av = *(const float4*)(A + (size_t)am*K + k0 + ak);
            if (ADD_ABIAS){
                av.x += abias[k0+ak+0]; av.y += abias[k0+ak+1];
                av.z += abias[k0+ak+2]; av.w += abias[k0+ak+3];
            }
            As[ak+0][arow]=av.x; As[ak+1][arow]=av.y; As[ak+2][arow]=av.z; As[ak+3][arow]=av.w;
            int brow = idx >> 5, bc = (idx & 31)*4;
            float4 bv = *(const float4*)(B + (size_t)(k0+brow)*N + n0 + bc);
            *(float4*)&Bs[brow][bc] = bv;
        }
        __syncthreads();
        #pragma unroll
        for (int kk = 0; kk < BK; ++kk){
            float a[8], b[8];
            *(float4*)&a[0] = *(const float4*)&As[kk][ty*8];
            *(float4*)&a[4] = *(const float4*)&As[kk][ty*8+4];
            *(float4*)&b[0] = *(const float4*)&Bs[kk][tx*8];
            *(float4*)&b[4] = *(const float4*)&Bs[kk][tx*8+4];
            #pragma unroll
            for (int i=0;i<8;++i)
                #pragma unroll
                for (int j=0;j<8;++j) acc[i][j] = fmaf(a[i], b[j], acc[i][j]);
        }
        __syncthreads();
    }
    #pragma unroll
    for (int i=0;i<8;++i){
        int m = m0 + ty*8 + i;
        if (m >= M) continue;
        #pragma unroll
        for (int j=0;j<8;j+=4){
            int n = n0 + tx*8 + j;
            float4 v; v.x=acc[i][j]; v.y=acc[i][j+1]; v.z=acc[i][j+2]; v.w=acc[i][j+3];
            if (HAS_BIAS){ v.x+=bias[n]; v.y+=bias[n+1]; v.z+=bias[n+2]; v.w+=bias[n+3]; }
            if (RELU){ v.x=fmaxf(v.x,0.f); v.y=fmaxf(v.y,0.f); v.z=fmaxf(v.z,0.f); v.w=fmaxf(v.w,0.f); }
            *(float4*)(C + (size_t)m*N + n) = v;
        }
    }
}

// ---------- GCN aggregation: gather over CSR, fused self + bias + relu ----------
template<int F>   // 256 or 128
__global__ __launch_bounds__(256) void gcn_agg_k(const float* __restrict__ h, const int* __restrict__ row_off,
        const int* __restrict__ srcs, const float* __restrict__ dinv, const float* __restrict__ bias,
        float* __restrict__ out)
{
    int wv = (blockIdx.x*256 + threadIdx.x) >> 6;   // node
    int lane = threadIdx.x & 63;
    if (wv >= NN) return;
    float di = dinv[wv];
    int r0 = row_off[wv], r1 = row_off[wv+1];
    if (F == 256){
        float4 acc;
        float4 v = *((const float4*)(h + (size_t)wv*F) + lane);
        float c = di*di;
        acc.x = v.x*c; acc.y = v.y*c; acc.z = v.z*c; acc.w = v.w*c;
        for (int p = r0; p < r1; ++p){
            int s = srcs[p];
            float coef = dinv[s]*di;
            float4 u = *((const float4*)(h + (size_t)s*F) + lane);
            acc.x = fmaf(u.x, coef, acc.x); acc.y = fmaf(u.y, coef, acc.y);
            acc.z = fmaf(u.z, coef, acc.z); acc.w = fmaf(u.w, coef, acc.w);
        }
        const float* bp = bias + lane*4;
        acc.x = fmaxf(acc.x + bp[0], 0.f); acc.y = fmaxf(acc.y + bp[1], 0.f);
        acc.z = fmaxf(acc.z + bp[2], 0.f); acc.w = fmaxf(acc.w + bp[3], 0.f);
        *((float4*)(out + (size_t)wv*F) + lane) = acc;
    } else {
        float2 acc;
        float2 v = *((const float2*)(h + (size_t)wv*F) + lane);
        float c = di*di;
        acc.x = v.x*c; acc.y = v.y*c;
        for (int p = r0; p < r1; ++p){
            int s = srcs[p];
            float coef = dinv[s]*di;
            float2 u = *((const float2*)(h + (size_t)s*F) + lane);
            acc.x = fmaf(u.x, coef, acc.x); acc.y = fmaf(u.y, coef, acc.y);
        }
        const float* bp = bias + lane*2;
        acc.x = fmaxf(acc.x + bp[0], 0.f); acc.y = fmaxf(acc.y + bp[1], 0.f);
        *((float2*)(out + (size_t)wv*F) + lane) = acc;
    }
}

// ---------- GAT ----------
__global__ __launch_bounds__(256) void gat_dots_k(const float* __restrict__ hg, const float* __restrict__ att_src,
        const float* __restrict__ att_dst, float* __restrict__ a_s, float* __restrict__ a_d){
    int wv = (blockIdx.x*256 + threadIdx.x) >> 6;   // over NN*HEADS
    int lane = threadIdx.x & 63;
    if (wv >= NN*HEADS) return;
    int n = wv >> 3, h = wv & 7;
    const float* row = hg + (size_t)n*GDIM + h*EMB;
    float2 v  = *(const float2*)(row + lane*2);
    float2 s2 = *(const float2*)(att_src + h*EMB + lane*2);
    float2 d2 = *(const float2*)(att_dst + h*EMB + lane*2);
    float ss = v.x*s2.x + v.y*s2.y;
    float sd = v.x*d2.x + v.y*d2.y;
    #pragma unroll
    for (int off=32; off; off>>=1){ ss += __shfl_down(ss, off, 64); sd += __shfl_down(sd, off, 64); }
    if (!lane){ a_s[wv] = ss; a_d[wv] = sd; }
}
// per (dst,head): softmax over CSR range; writes sorted numerators + self alpha + 1/denom
__global__ __launch_bounds__(256) void gat_soft_k(const int* __restrict__ row_off, const int* __restrict__ srcs,
        const float* __restrict__ a_s, const float* __restrict__ a_d,
        float* __restrict__ ex_sorted, float* __restrict__ alpha_self, float* __restrict__ inv_den)
{
    int t = blockIdx.x*256 + threadIdx.x;   // NN*8, divisible by 256
    if (t >= NN*HEADS) return;
    int d = t >> 3, h = t & 7;
    float ad = a_d[t];
    float eself = lrelu(a_s[t] + ad);
    float m = eself;
    int r0 = row_off[d], r1 = row_off[d+1];
    for (int p = r0; p < r1; ++p){
        int s = srcs[p];
        m = fmaxf(m, lrelu(a_s[s*HEADS + h] + ad));
    }
    float den = expf(eself - m);
    for (int p = r0; p < r1; ++p){
        int s = srcs[p];
        float x = expf(lrelu(a_s[s*HEADS + h] + ad) - m);
        ex_sorted[(size_t)p*HEADS + h] = x;
        den += x;
    }
    float id = 1.f / den;
    alpha_self[t] = expf(eself - m) * id;
    inv_den[t]    = id;
}
// per dst node: out[d,:] = alpha_self*hg[d,:] + sum_e alpha_e*hg[src,:]
__global__ __launch_bounds__(256) void gat_out_k(const float* __restrict__ hg, const int* __restrict__ row_off,
        const int* __restrict__ srcs, const float* __restrict__ exs, const float* __restrict__ aself,
        const float* __restrict__ idn, float* __restrict__ gat)
{
    int wv = (blockIdx.x*256 + threadIdx.x) >> 6;
    int lane = threadIdx.x & 63;
    if (wv >= NN) return;
    int hh = lane >> 3;
    float as = aself[wv*HEADS + hh];
    float id = idn[wv*HEADS + hh];
    float4 acc[4];
    const float4* rp = (const float4*)(hg + (size_t)wv*GDIM + lane*16);
    #pragma unroll
    for (int q = 0; q < 4; ++q){
        float4 v = rp[q];
        acc[q].x = v.x*as; acc[q].y = v.y*as; acc[q].z = v.z*as; acc[q].w = v.w*as;
    }
    int r0 = row_off[wv], r1 = row_off[wv+1];
    for (int p = r0; p < r1; ++p){
        int s = srcs[p];
        float al = exs[(size_t)p*HEADS + hh] * id;
        const float4* sp = (const float4*)(hg + (size_t)s*GDIM + lane*16);
        #pragma unroll
        for (int q = 0; q < 4; ++q){
            float4 v = sp[q];
            acc[q].x = fmaf(v.x, al, acc[q].x); acc[q].y = fmaf(v.y, al, acc[q].y);
            acc[q].z = fmaf(v.z, al, acc[q].z); acc[q].w = fmaf(v.w, al, acc[q].w);
        }
    }
    float4* op = (float4*)(gat + (size_t)wv*GDIM + lane*16);
    #pragma unroll
    for (int q = 0; q < 4; ++q) op[q] = acc[q];
}

// ---------- head: logits -> sigmoid ----------
__global__ __launch_bounds__(256) void head_k(const float* __restrict__ z, const float* __restrict__ Wh2,
        const float* __restrict__ bh2, float* __restrict__ w){
    int wv = (blockIdx.x*256 + threadIdx.x) >> 6;
    int lane = threadIdx.x & 63;
    if (wv >= NN) return;
    float4 zv = *(const float4*)(z + (size_t)wv*HIDDIM + lane*4);
    float4 wv4 = *(const float4*)(Wh2 + lane*4);
    float s = zv.x*wv4.x + zv.y*wv4.y + zv.z*wv4.z + zv.w*wv4.w;
    #pragma unroll
    for (int off=32; off; off>>=1) s += __shfl_down(s, off, 64);
    if (!lane){
        float logit = s + bh2[0];
        w[wv] = 1.f / (1.f + expf(-logit));
    }
}

// ---------- global softmax ----------
__global__ void red_init_k(float* red){
    if (threadIdx.x == 0){ ((unsigned*)red)[0] = 0u; red[1] = 0.f; }
}
__global__ __launch_bounds__(256) void red_max_k(const float* __restrict__ w, float* __restrict__ red){
    __shared__ float s[256];
    float v = 0.f;
    for (int i = blockIdx.x*256 + threadIdx.x; i < NN; i += gridDim.x*256) v = fmaxf(v, w[i]);
    s[threadIdx.x] = v; __syncthreads();
    for (int off=128; off; off>>=1){
        if (threadIdx.x < off) s[threadIdx.x] = fmaxf(s[threadIdx.x], s[threadIdx.x+off]);
        __syncthreads();
    }
    if (!threadIdx.x) atomicMax((unsigned*)red, ordU(s[0]));
}
__global__ __launch_bounds__(256) void red_sum_k(const float* __restrict__ w, float* __restrict__ red){
    float mx = unordU(((const unsigned*)red)[0]);
    __shared__ float s[256];
    float v = 0.f;
    for (int i = blockIdx.x*256 + threadIdx.x; i < NN; i += gridDim.x*256) v += expf(w[i]-mx);
    s[threadIdx.x] = v; __syncthreads();
    for (int off=128; off; off>>=1){
        if (threadIdx.x < off) s[threadIdx.x] += s[threadIdx.x+off];
        __syncthreads();
    }
    if (!threadIdx.x) unsafeAtomicAdd(&red[1], s[0]);
}
__global__ __launch_bounds__(256) void final_k(const float* __restrict__ w, const float* __restrict__ red,
                                               float* __restrict__ out){
    int i = blockIdx.x*256 + threadIdx.x;
    if (i >= NN) return;
    float mx = unordU(((const unsigned*)red)[0]);
    out[i] = expf(w[i]-mx) / red[1];
}

// ---------- launch ----------
extern "C" void kernel_launch(void* const* d_in, const int* in_sizes, int n_in,
                              void* d_out, int out_size, void* d_ws, size_t ws_size,
                              hipStream_t stream) {
    const float* x   = (const float*)d_in[0];
    const int*   ei  = (const int*)  d_in[1];
    const float* W1  = (const float*)d_in[2];
    const float* b1  = (const float*)d_in[3];
    const float* W2  = (const float*)d_in[4];
    const float* b2  = (const float*)d_in[5];
    const float* W3  = (const float*)d_in[6];
    const float* b3  = (const float*)d_in[7];
    const float* Wg  = (const float*)d_in[8];
    const float* att_src = (const float*)d_in[9];
    const float* att_dst = (const float*)d_in[10];
    const float* bg  = (const float*)d_in[11];
    const float* Wh1 = (const float*)d_in[12];
    const float* bh1 = (const float*)d_in[13];
    const float* Wh2 = (const float*)d_in[14];
    const float* bh2 = (const float*)d_in[15];
    float* out = (float*)d_out;

    const int E = in_sizes[1] / 2;
    const int* src = ei;
    const int* dst = ei + E;

    float* ws = (float*)d_ws;
    size_t o = 0;
    auto alloc = [&](size_t n){ float* p = ws + o; o += n; return p; };
    float* dinv   = alloc(NN);
    float* bufA   = alloc((size_t)NN*HIDDIM);
    float* bufB   = alloc((size_t)NN*HIDDIM);
    float* hg     = alloc((size_t)NN*GDIM);
    float* gat    = alloc((size_t)NN*GDIM);
    float* a_s    = alloc((size_t)NN*HEADS);
    float* a_d    = alloc((size_t)NN*HEADS);
    float* aself  = alloc((size_t)NN*HEADS);
    float* idn    = alloc((size_t)NN*HEADS);
    float* exs    = alloc((size_t)E*HEADS);
    float* wsig   = alloc(NN);
    float* red    = alloc(8);
    int* cnt      = (int*)alloc(NN);      // cnt and cursor contiguous for one zero pass
    int* cursor   = (int*)alloc(NN);
    int* row_off  = (int*)alloc(NN+1);
    int* src_srt  = (int*)alloc(E);

    const int nb  = (NN + 255)/256;
    const int eb  = (E + 255)/256;
    const int nwb = (NN + 3)/4;          // 1 wave/node, 4 waves/block
    const dim3 blk(256);

    // ---- CSR build + dinv ----
    zero_int_k<<<(2*NN + 255)/256, blk, 0, stream>>>(cnt, 2*NN);
    hist_k<<<eb, blk, 0, stream>>>(dst, cnt, E);
    scan_k<<<1, 1024, 0, stream>>>(cnt, row_off);
    dinv_k<<<nb, blk, 0, stream>>>(cnt, dinv);
    scatter_k<<<eb, blk, 0, stream>>>(src, dst, row_off, cursor, src_srt, E);

    const int MT = (NN + 127)/128;      // 157

    // GCN layer 1 (K=256,N=256)
    gemm_k<false,false,false><<<dim3(2, MT), blk, 0, stream>>>(x, W1, nullptr, nullptr, bufA, NN, 256, 256);
    gcn_agg_k<256><<<nwb, blk, 0, stream>>>(bufA, row_off, src_srt, dinv, b1, bufB);
    // GCN layer 2
    gemm_k<false,false,false><<<dim3(2, MT), blk, 0, stream>>>(bufB, W2, nullptr, nullptr, bufA, NN, 256, 256);
    gcn_agg_k<256><<<nwb, blk, 0, stream>>>(bufA, row_off, src_srt, dinv, b2, bufB);
    // GCN layer 3 (K=256,N=128)
    gemm_k<false,false,false><<<dim3(1, MT), blk, 0, stream>>>(bufB, W3, nullptr, nullptr, bufA, NN, 128, 256);
    gcn_agg_k<128><<<nwb, blk, 0, stream>>>(bufA, row_off, src_srt, dinv, b3, bufB);

    // GAT projection (K=128,N=1024)  A rows are bufB[:,0:128]? No: layer3 out is bufB [NN,128]
    gemm_k<false,false,false><<<dim3(8, MT), blk, 0, stream>>>(bufB, Wg, nullptr, nullptr, hg, NN, 1024, 128);
    gat_dots_k<<<(NN*HEADS)/4, blk, 0, stream>>>(hg, att_src, att_dst, a_s, a_d);
    gat_soft_k<<<(NN*HEADS)/256, blk, 0, stream>>>(row_off, src_srt, a_s, a_d, exs, aself, idn);
    gat_out_k<<<nwb, blk, 0, stream>>>(hg, row_off, src_srt, exs, aself, idn, gat);

    // head MLP (K=1024,N=256) with fused +bg on A and relu+bh1 on out
    gemm_k<true,true,true><<<dim3(2, MT), blk, 0, stream>>>(gat, Wh1, bh1, bg, bufA, NN, 256, 1024);
    head_k<<<nwb, blk, 0, stream>>>(bufA, Wh2, bh2, wsig);

    // global softmax over sigmoid(logits)
    red_init_k<<<1, 64, 0, stream>>>(red);
    red_max_k<<<40, blk, 0, stream>>>(wsig, red);
    red_sum_k<<<40, blk, 0, stream>>>(wsig, red);
    final_k<<<nb, blk, 0, stream>>>(wsig, red, out);
}

// Round 3
// 421.927 us; speedup vs baseline: 25.5427x; 1.8550x over previous
//
#include <hip/hip_runtime.h>
#include <math.h>

#define NN 20000
#define HEADS 8
#define GDIM 1024
#define M_PAD 20096   // 157 * 128

typedef _Float16 f16;
typedef f16 f16x2  __attribute__((ext_vector_type(2)));
typedef f16 f16x4v __attribute__((ext_vector_type(4)));
typedef f16 f16x8v __attribute__((ext_vector_type(8)));
typedef float f32x4 __attribute__((ext_vector_type(4)));

// ---------- helpers ----------
__device__ __forceinline__ float lrelu(float x){ return x > 0.f ? x : 0.2f*x; }
__device__ __forceinline__ unsigned ordU(float f){
    unsigned u = __float_as_uint(f);
    return (u & 0x80000000u) ? ~u : (u | 0x80000000u);
}
__device__ __forceinline__ float unordU(unsigned u){
    return (u & 0x80000000u) ? __uint_as_float(u & 0x7fffffffu) : __uint_as_float(~u);
}

// ---------- CSR build ----------
__global__ __launch_bounds__(256) void zero_int_k(int* __restrict__ p, int n){
    int i = blockIdx.x*256 + threadIdx.x;
    if (i < n) p[i] = 0;
}
__global__ __launch_bounds__(256) void hist_k(const int* __restrict__ dst, int* __restrict__ cnt, int E){
    int i = blockIdx.x*256 + threadIdx.x;
    if (i < E) atomicAdd(&cnt[dst[i]], 1);
}
__global__ __launch_bounds__(1024) void scan_k(const int* __restrict__ cnt, int* __restrict__ row_off,
                                               float* __restrict__ dinv){
    __shared__ int tot[1024];
    int t = threadIdx.x;
    const int CH = 20;
    int base = t*CH;
    int loc[CH]; int s = 0;
    #pragma unroll
    for (int i = 0; i < CH; ++i){
        int v = (base+i < NN) ? cnt[base+i] : 0;
        loc[i] = s; s += v;
    }
    tot[t] = s; __syncthreads();
    for (int off = 1; off < 1024; off <<= 1){
        int v = (t >= off) ? tot[t-off] : 0;
        __syncthreads();
        tot[t] += v;
        __syncthreads();
    }
    int pre = (t == 0) ? 0 : tot[t-1];
    #pragma unroll
    for (int i = 0; i < CH; ++i)
        if (base+i < NN){
            row_off[base+i] = pre + loc[i];
            dinv[base+i] = rsqrtf((float)cnt[base+i] + 1.f);
        }
    if (t == 1023) row_off[NN] = tot[1023];
}
__global__ __launch_bounds__(256) void scatter_k(const int* __restrict__ src, const int* __restrict__ dst,
        const int* __restrict__ row_off, int* __restrict__ cursor, int* __restrict__ src_sorted, int E){
    int i = blockIdx.x*256 + threadIdx.x;
    if (i >= E) return;
    int d = dst[i];
    int pos = row_off[d] + atomicAdd(&cursor[d], 1);
    src_sorted[pos] = src[i];
}

// ---------- fp32 -> fp16 conversion: x (padded) + 5 transposed weights ----------
__global__ __launch_bounds__(256) void cvt_all_k(const float* __restrict__ x,
        const float* __restrict__ W1, const float* __restrict__ W2, const float* __restrict__ W3,
        const float* __restrict__ Wg, const float* __restrict__ Wh1,
        f16* __restrict__ xh, f16* __restrict__ wt1, f16* __restrict__ wt2, f16* __restrict__ wt3,
        f16* __restrict__ wtg, f16* __restrict__ wth1)
{
    int t = blockIdx.x*256 + threadIdx.x;
    const int NX = M_PAD*256;
    if (t < NX){
        int row = t >> 8;
        xh[t] = (row < NN) ? (f16)x[t] : (f16)0.f;
        return;
    }
    t -= NX;
    if (t < 65536){ int k = t >> 8, n = t & 255; wt1[n*256 + k] = (f16)W1[t]; return; }
    t -= 65536;
    if (t < 65536){ int k = t >> 8, n = t & 255; wt2[n*256 + k] = (f16)W2[t]; return; }
    t -= 65536;
    if (t < 32768){ int k = t >> 7, n = t & 127; wt3[n*256 + k] = (f16)W3[t]; return; }
    t -= 32768;
    if (t < 131072){ int k = t >> 10, n = t & 1023; wtg[n*128 + k] = (f16)Wg[t]; return; }
    t -= 131072;
    if (t < 262144){ int k = t >> 8, n = t & 255; wth1[n*1024 + k] = (f16)Wh1[t]; return; }
}

// ---------- fp16 MFMA GEMM: C[M,N] = A[M,K] @ Bt[N,K]^T  ----------
// 128x128 tile, BK=32, 4 waves (2x2), each wave 64x64 via 4x4 mfma_16x16x32_f16.
template<bool OUT_F16, bool RELU, bool HAS_BIAS>
__global__ __launch_bounds__(256,2) void gemm_f16_k(const f16* __restrict__ A, const f16* __restrict__ Bt,
        const float* __restrict__ bias, void* __restrict__ C, int M, int N, int K)
{
    __shared__ __align__(16) f16 As[128*32];
    __shared__ __align__(16) f16 Bs[128*32];
    const int tid  = threadIdx.x;
    const int lane = tid & 63;
    const int wave = tid >> 6;
    const int wm = (wave >> 1) * 64, wn = (wave & 1) * 64;
    const int l15 = lane & 15, quad = lane >> 4;
    const int m0 = blockIdx.y * 128, n0 = blockIdx.x * 128;

    // staging: thread covers 32 B = two 16-B chunks (rows r1 and r1+64)
    const int r1 = tid >> 2;
    const int ce = (tid & 3) * 8;          // f16 element offset within 32-elem row
    const f16* A0 = A + (size_t)(m0 + r1) * K + ce;
    const f16* A1 = A0 + (size_t)64 * K;
    const f16* B0 = Bt + (size_t)(n0 + r1) * K + ce;
    const f16* B1 = B0 + (size_t)64 * K;

    f32x4 acc[4][4] = {};
    for (int k0 = 0; k0 < K; k0 += 32){
        *(uint4*)&As[tid*8]        = *(const uint4*)(A0 + k0);
        *(uint4*)&As[tid*8 + 2048] = *(const uint4*)(A1 + k0);
        *(uint4*)&Bs[tid*8]        = *(const uint4*)(B0 + k0);
        *(uint4*)&Bs[tid*8 + 2048] = *(const uint4*)(B1 + k0);
        __syncthreads();
        f16x8v af[4], bf[4];
        #pragma unroll
        for (int i = 0; i < 4; ++i){
            af[i] = *(const f16x8v*)&As[(wm + i*16 + l15)*32 + quad*8];
            bf[i] = *(const f16x8v*)&Bs[(wn + i*16 + l15)*32 + quad*8];
        }
        #pragma unroll
        for (int i = 0; i < 4; ++i)
            #pragma unroll
            for (int j = 0; j < 4; ++j)
                acc[i][j] = __builtin_amdgcn_mfma_f32_16x16x32_f16(af[i], bf[j], acc[i][j], 0, 0, 0);
        __syncthreads();
    }
    #pragma unroll
    for (int i = 0; i < 4; ++i){
        int rb = m0 + wm + i*16 + quad*4;
        #pragma unroll
        for (int j = 0; j < 4; ++j){
            int col = n0 + wn + j*16 + l15;
            float bv = HAS_BIAS ? bias[col] : 0.f;
            #pragma unroll
            for (int r = 0; r < 4; ++r){
                int row = rb + r;
                if (row >= M) continue;
                float v = acc[i][j][r] + bv;
                if (RELU) v = fmaxf(v, 0.f);
                if (OUT_F16) ((f16*)C)[(size_t)row*N + col] = (f16)v;
                else       ((float*)C)[(size_t)row*N + col] = v;
            }
        }
    }
}

// ---------- GCN aggregation (fp16 in/out, fp32 acc): fused self + bias + relu ----------
template<int F>   // 256 or 128
__global__ __launch_bounds__(256) void gcn_agg_f16_k(const f16* __restrict__ h, const int* __restrict__ row_off,
        const int* __restrict__ srcs, const float* __restrict__ dinv, const float* __restrict__ bias,
        f16* __restrict__ out)
{
    int wv = (blockIdx.x*256 + threadIdx.x) >> 6;
    int lane = threadIdx.x & 63;
    if (wv >= NN) return;
    float di = dinv[wv];
    int r0 = row_off[wv], r1 = row_off[wv+1];
    if (F == 256){
        f16x4v v = *(const f16x4v*)(h + (size_t)wv*256 + lane*4);
        float c = di*di;
        float a0 = (float)v[0]*c, a1 = (float)v[1]*c, a2 = (float)v[2]*c, a3 = (float)v[3]*c;
        for (int p = r0; p < r1; ++p){
            int s = srcs[p];
            float coef = dinv[s]*di;
            f16x4v u = *(const f16x4v*)(h + (size_t)s*256 + lane*4);
            a0 = fmaf((float)u[0], coef, a0); a1 = fmaf((float)u[1], coef, a1);
            a2 = fmaf((float)u[2], coef, a2); a3 = fmaf((float)u[3], coef, a3);
        }
        float4 bv = *(const float4*)(bias + lane*4);
        f16x4v o;
        o[0] = (f16)fmaxf(a0 + bv.x, 0.f); o[1] = (f16)fmaxf(a1 + bv.y, 0.f);
        o[2] = (f16)fmaxf(a2 + bv.z, 0.f); o[3] = (f16)fmaxf(a3 + bv.w, 0.f);
        *(f16x4v*)(out + (size_t)wv*256 + lane*4) = o;
    } else {
        f16x2 v = *(const f16x2*)(h + (size_t)wv*128 + lane*2);
        float c = di*di;
        float a0 = (float)v[0]*c, a1 = (float)v[1]*c;
        for (int p = r0; p < r1; ++p){
            int s = srcs[p];
            float coef = dinv[s]*di;
            f16x2 u = *(const f16x2*)(h + (size_t)s*128 + lane*2);
            a0 = fmaf((float)u[0], coef, a0); a1 = fmaf((float)u[1], coef, a1);
        }
        float2 bv = *(const float2*)(bias + lane*2);
        f16x2 o;
        o[0] = (f16)fmaxf(a0 + bv.x, 0.f); o[1] = (f16)fmaxf(a1 + bv.y, 0.f);
        *(f16x2*)(out + (size_t)wv*128 + lane*2) = o;
    }
}

// ---------- GAT ----------
__global__ __launch_bounds__(256) void gat_dots_k(const f16* __restrict__ hg, const float* __restrict__ att_src,
        const float* __restrict__ att_dst, float* __restrict__ a_s, float* __restrict__ a_d){
    int wv = (blockIdx.x*256 + threadIdx.x) >> 6;   // over NN*HEADS
    int lane = threadIdx.x & 63;
    if (wv >= NN*HEADS) return;
    int n = wv >> 3, h = wv & 7;
    const f16* row = hg + (size_t)n*GDIM + h*128;
    f16x2 v  = *(const f16x2*)(row + lane*2);
    float2 s2 = *(const float2*)(att_src + h*128 + lane*2);
    float2 d2 = *(const float2*)(att_dst + h*128 + lane*2);
    float vx = (float)v[0], vy = (float)v[1];
    float ss = vx*s2.x + vy*s2.y;
    float sd = vx*d2.x + vy*d2.y;
    #pragma unroll
    for (int off=32; off; off>>=1){ ss += __shfl_down(ss, off, 64); sd += __shfl_down(sd, off, 64); }
    if (!lane){ a_s[wv] = ss; a_d[wv] = sd; }
}
__global__ __launch_bounds__(256) void gat_soft_k(const int* __restrict__ row_off, const int* __restrict__ srcs,
        const float* __restrict__ a_s, const float* __restrict__ a_d,
        float* __restrict__ ex_sorted, float* __restrict__ alpha_self, float* __restrict__ inv_den)
{
    int t = blockIdx.x*256 + threadIdx.x;
    if (t >= NN*HEADS) return;
    int d = t >> 3, h = t & 7;
    float ad = a_d[t];
    float eself = lrelu(a_s[t] + ad);
    float m = eself;
    int r0 = row_off[d], r1 = row_off[d+1];
    for (int p = r0; p < r1; ++p){
        int s = srcs[p];
        m = fmaxf(m, lrelu(a_s[s*HEADS + h] + ad));
    }
    float den = expf(eself - m);
    for (int p = r0; p < r1; ++p){
        int s = srcs[p];
        float x = expf(lrelu(a_s[s*HEADS + h] + ad) - m);
        ex_sorted[(size_t)p*HEADS + h] = x;
        den += x;
    }
    float id = 1.f / den;
    alpha_self[t] = expf(eself - m) * id;
    inv_den[t]    = id;
}
// per dst node: gat[d,:] = bg + alpha_self*hg[d,:] + sum_e alpha_e*hg[src,:]   (fp16 out)
__global__ __launch_bounds__(256) void gat_out_f16_k(const f16* __restrict__ hg, const int* __restrict__ row_off,
        const int* __restrict__ srcs, const float* __restrict__ exs, const float* __restrict__ aself,
        const float* __restrict__ idn, const float* __restrict__ bg, f16* __restrict__ gat)
{
    int wv = (blockIdx.x*256 + threadIdx.x) >> 6;
    int lane = threadIdx.x & 63;
    if (wv >= NN) return;
    int hh = lane >> 3;
    float as = aself[wv*HEADS + hh];
    float id = idn[wv*HEADS + hh];
    float acc[16];
    const f16* rp = hg + (size_t)wv*GDIM + lane*16;
    f16x8v v0 = *(const f16x8v*)rp, v1 = *(const f16x8v*)(rp + 8);
    #pragma unroll
    for (int q = 0; q < 8; ++q){ acc[q] = (float)v0[q]*as; acc[8+q] = (float)v1[q]*as; }
    int r0 = row_off[wv], r1 = row_off[wv+1];
    for (int p = r0; p < r1; ++p){
        int s = srcs[p];
        float al = exs[(size_t)p*HEADS + hh] * id;
        const f16* sp = hg + (size_t)s*GDIM + lane*16;
        f16x8v u0 = *(const f16x8v*)sp, u1 = *(const f16x8v*)(sp + 8);
        #pragma unroll
        for (int q = 0; q < 8; ++q){
            acc[q]   = fmaf((float)u0[q], al, acc[q]);
            acc[8+q] = fmaf((float)u1[q], al, acc[8+q]);
        }
    }
    const float* bp = bg + lane*16;
    f16x8v o0, o1;
    #pragma unroll
    for (int q = 0; q < 8; ++q){
        o0[q] = (f16)(acc[q]   + bp[q]);
        o1[q] = (f16)(acc[8+q] + bp[8+q]);
    }
    f16* op = gat + (size_t)wv*GDIM + lane*16;
    *(f16x8v*)op = o0; *(f16x8v*)(op + 8) = o1;
}

// ---------- head: logits -> sigmoid ----------
__global__ __launch_bounds__(256) void head_k(const float* __restrict__ z, const float* __restrict__ Wh2,
        const float* __restrict__ bh2, float* __restrict__ w){
    int wv = (blockIdx.x*256 + threadIdx.x) >> 6;
    int lane = threadIdx.x & 63;
    if (wv >= NN) return;
    float4 zv = *(const float4*)(z + (size_t)wv*256 + lane*4);
    float4 wv4 = *(const float4*)(Wh2 + lane*4);
    float s = zv.x*wv4.x + zv.y*wv4.y + zv.z*wv4.z + zv.w*wv4.w;
    #pragma unroll
    for (int off=32; off; off>>=1) s += __shfl_down(s, off, 64);
    if (!lane){
        float logit = s + bh2[0];
        w[wv] = 1.f / (1.f + expf(-logit));
    }
}

// ---------- global softmax ----------
__global__ void red_init_k(float* red){
    if (threadIdx.x == 0){ ((unsigned*)red)[0] = 0u; red[1] = 0.f; }
}
__global__ __launch_bounds__(256) void red_max_k(const float* __restrict__ w, float* __restrict__ red){
    __shared__ float s[256];
    float v = 0.f;
    for (int i = blockIdx.x*256 + threadIdx.x; i < NN; i += gridDim.x*256) v = fmaxf(v, w[i]);
    s[threadIdx.x] = v; __syncthreads();
    for (int off=128; off; off>>=1){
        if (threadIdx.x < off) s[threadIdx.x] = fmaxf(s[threadIdx.x], s[threadIdx.x+off]);
        __syncthreads();
    }
    if (!threadIdx.x) atomicMax((unsigned*)red, ordU(s[0]));
}
__global__ __launch_bounds__(256) void red_sum_k(const float* __restrict__ w, float* __restrict__ red){
    float mx = unordU(((const unsigned*)red)[0]);
    __shared__ float s[256];
    float v = 0.f;
    for (int i = blockIdx.x*256 + threadIdx.x; i < NN; i += gridDim.x*256) v += expf(w[i]-mx);
    s[threadIdx.x] = v; __syncthreads();
    for (int off=128; off; off>>=1){
        if (threadIdx.x < off) s[threadIdx.x] += s[threadIdx.x+off];
        __syncthreads();
    }
    if (!threadIdx.x) unsafeAtomicAdd(&red[1], s[0]);
}
__global__ __launch_bounds__(256) void final_k(const float* __restrict__ w, const float* __restrict__ red,
                                               float* __restrict__ out){
    int i = blockIdx.x*256 + threadIdx.x;
    if (i >= NN) return;
    float mx = unordU(((const unsigned*)red)[0]);
    out[i] = expf(w[i]-mx) / red[1];
}

// ---------- launch ----------
extern "C" void kernel_launch(void* const* d_in, const int* in_sizes, int n_in,
                              void* d_out, int out_size, void* d_ws, size_t ws_size,
                              hipStream_t stream) {
    const float* x   = (const float*)d_in[0];
    const int*   ei  = (const int*)  d_in[1];
    const float* W1  = (const float*)d_in[2];
    const float* b1  = (const float*)d_in[3];
    const float* W2  = (const float*)d_in[4];
    const float* b2  = (const float*)d_in[5];
    const float* W3  = (const float*)d_in[6];
    const float* b3  = (const float*)d_in[7];
    const float* Wg  = (const float*)d_in[8];
    const float* att_src = (const float*)d_in[9];
    const float* att_dst = (const float*)d_in[10];
    const float* bg  = (const float*)d_in[11];
    const float* Wh1 = (const float*)d_in[12];
    const float* bh1 = (const float*)d_in[13];
    const float* Wh2 = (const float*)d_in[14];
    const float* bh2 = (const float*)d_in[15];
    float* out = (float*)d_out;

    const int E = in_sizes[1] / 2;
    const int* src = ei;
    const int* dst = ei + E;

    float* ws = (float*)d_ws;
    size_t o = 0;
    auto alloc = [&](size_t nfloats){ float* p = ws + o; o += (nfloats + 3) & ~(size_t)3; return p; };
    f16* xh    = (f16*)alloc((size_t)M_PAD*256/2);
    f16* wt1   = (f16*)alloc(65536/2);
    f16* wt2   = (f16*)alloc(65536/2);
    f16* wt3   = (f16*)alloc(32768/2);
    f16* wtg   = (f16*)alloc(131072/2);
    f16* wth1  = (f16*)alloc(262144/2);
    f16* fH    = (f16*)alloc((size_t)M_PAD*256/2);   // h1,h2,h3
    f16* fG    = (f16*)alloc((size_t)M_PAD*256/2);   // g1,g2,g3
    f16* hg    = (f16*)alloc((size_t)M_PAD*GDIM/2);
    f16* gat   = (f16*)alloc((size_t)M_PAD*GDIM/2);
    float* z    = alloc((size_t)M_PAD*256);
    float* dinv = alloc(NN);
    float* a_s  = alloc((size_t)NN*HEADS);
    float* a_d  = alloc((size_t)NN*HEADS);
    float* aself= alloc((size_t)NN*HEADS);
    float* idn  = alloc((size_t)NN*HEADS);
    float* exs  = alloc((size_t)E*HEADS);
    float* wsig = alloc(NN);
    float* red  = alloc(8);
    int* cnt    = (int*)alloc(NN);     // cnt+cursor contiguous for one zero pass
    int* cursor = (int*)alloc(NN);
    int* row_off= (int*)alloc(NN+1);
    int* src_srt= (int*)alloc(E);

    const int nb  = (NN + 255)/256;
    const int eb  = (E + 255)/256;
    const int nwb = (NN + 3)/4;
    const dim3 blk(256);

    // CSR + dinv
    zero_int_k<<<(2*NN + 255)/256, blk, 0, stream>>>(cnt, 2*NN);
    hist_k<<<eb, blk, 0, stream>>>(dst, cnt, E);
    scan_k<<<1, 1024, 0, stream>>>(cnt, row_off, dinv);
    scatter_k<<<eb, blk, 0, stream>>>(src, dst, row_off, cursor, src_srt, E);

    // conversions (x padded + 5 transposed weights)
    const int CVT_T = M_PAD*256 + 65536 + 65536 + 32768 + 131072 + 262144;
    cvt_all_k<<<CVT_T/256, blk, 0, stream>>>(x, W1, W2, W3, Wg, Wh1, xh, wt1, wt2, wt3, wtg, wth1);

    const int MT = M_PAD/128;   // 157

    // GCN 1
    gemm_f16_k<true,false,false><<<dim3(2, MT), blk, 0, stream>>>(xh, wt1, nullptr, fH, NN, 256, 256);
    gcn_agg_f16_k<256><<<nwb, blk, 0, stream>>>(fH, row_off, src_srt, dinv, b1, fG);
    // GCN 2
    gemm_f16_k<true,false,false><<<dim3(2, MT), blk, 0, stream>>>(fG, wt2, nullptr, fH, NN, 256, 256);
    gcn_agg_f16_k<256><<<nwb, blk, 0, stream>>>(fH, row_off, src_srt, dinv, b2, fG);
    // GCN 3 (N=128)
    gemm_f16_k<true,false,false><<<dim3(1, MT), blk, 0, stream>>>(fG, wt3, nullptr, fH, NN, 128, 256);
    gcn_agg_f16_k<128><<<nwb, blk, 0, stream>>>(fH, row_off, src_srt, dinv, b3, fG);

    // GAT projection (K=128, N=1024)
    gemm_f16_k<true,false,false><<<dim3(8, MT), blk, 0, stream>>>(fG, wtg, nullptr, hg, NN, 1024, 128);
    gat_dots_k<<<(NN*HEADS)/4, blk, 0, stream>>>(hg, att_src, att_dst, a_s, a_d);
    gat_soft_k<<<(NN*HEADS)/256, blk, 0, stream>>>(row_off, src_srt, a_s, a_d, exs, aself, idn);
    gat_out_f16_k<<<nwb, blk, 0, stream>>>(hg, row_off, src_srt, exs, aself, idn, bg, gat);

    // head MLP (K=1024, N=256): +bh1, relu, fp32 out
    gemm_f16_k<false,true,true><<<dim3(2, MT), blk, 0, stream>>>(gat, wth1, bh1, z, NN, 256, 1024);
    head_k<<<nwb, blk, 0, stream>>>(z, Wh2, bh2, wsig);

    // global softmax
    red_init_k<<<1, 64, 0, stream>>>(red);
    red_max_k<<<40, blk, 0, stream>>>(wsig, red);
    red_sum_k<<<40, blk, 0, stream>>>(wsig, red);
    final_k<<<nb, blk, 0, stream>>>(wsig, red, out);
}

// Round 4
// 414.688 us; speedup vs baseline: 25.9885x; 1.0175x over previous
//
#include <hip/hip_runtime.h>
#include <math.h>

#define NN 20000
#define HEADS 8
#define GDIM 1024
#define M_PAD 20096   // 157 * 128

typedef _Float16 f16;
typedef f16 f16x2  __attribute__((ext_vector_type(2)));
typedef f16 f16x4v __attribute__((ext_vector_type(4)));
typedef f16 f16x8v __attribute__((ext_vector_type(8)));
typedef float f32x4 __attribute__((ext_vector_type(4)));

// ---------- helpers ----------
__device__ __forceinline__ float lrelu(float x){ return x > 0.f ? x : 0.2f*x; }
__device__ __forceinline__ unsigned ordU(float f){
    unsigned u = __float_as_uint(f);
    return (u & 0x80000000u) ? ~u : (u | 0x80000000u);
}
__device__ __forceinline__ float unordU(unsigned u){
    return (u & 0x80000000u) ? __uint_as_float(u & 0x7fffffffu) : __uint_as_float(~u);
}

// ---------- CSR build ----------
__global__ __launch_bounds__(256) void zero_int_k(int* __restrict__ p, int n){
    int i = blockIdx.x*256 + threadIdx.x;
    if (i < n) p[i] = 0;
}
__global__ __launch_bounds__(256) void hist_k(const int* __restrict__ dst, int* __restrict__ cnt, int E){
    int i = blockIdx.x*256 + threadIdx.x;
    if (i < E) atomicAdd(&cnt[dst[i]], 1);
}
__global__ __launch_bounds__(1024) void scan_k(const int* __restrict__ cnt, int* __restrict__ row_off,
                                               float* __restrict__ dinv){
    __shared__ int tot[1024];
    int t = threadIdx.x;
    const int CH = 20;
    int base = t*CH;
    int loc[CH]; int s = 0;
    #pragma unroll
    for (int i = 0; i < CH; ++i){
        int v = (base+i < NN) ? cnt[base+i] : 0;
        loc[i] = s; s += v;
    }
    tot[t] = s; __syncthreads();
    for (int off = 1; off < 1024; off <<= 1){
        int v = (t >= off) ? tot[t-off] : 0;
        __syncthreads();
        tot[t] += v;
        __syncthreads();
    }
    int pre = (t == 0) ? 0 : tot[t-1];
    #pragma unroll
    for (int i = 0; i < CH; ++i)
        if (base+i < NN){
            row_off[base+i] = pre + loc[i];
            dinv[base+i] = rsqrtf((float)cnt[base+i] + 1.f);
        }
    if (t == 1023) row_off[NN] = tot[1023];
}
__global__ __launch_bounds__(256) void scatter_k(const int* __restrict__ src, const int* __restrict__ dst,
        const int* __restrict__ row_off, int* __restrict__ cursor, int* __restrict__ src_sorted, int E){
    int i = blockIdx.x*256 + threadIdx.x;
    if (i >= E) return;
    int d = dst[i];
    int pos = row_off[d] + atomicAdd(&cursor[d], 1);
    src_sorted[pos] = src[i];
}

// ---------- weight transpose+convert: fp32 [K][N] -> fp16 [N][K] ----------
__global__ __launch_bounds__(256) void cvt_w_k(
        const float* __restrict__ W1, const float* __restrict__ W2, const float* __restrict__ W3,
        const float* __restrict__ Wg, const float* __restrict__ Wh1,
        f16* __restrict__ wt1, f16* __restrict__ wt2, f16* __restrict__ wt3,
        f16* __restrict__ wtg, f16* __restrict__ wth1)
{
    int t = blockIdx.x*256 + threadIdx.x;
    if (t < 65536){ int k = t >> 8, n = t & 255; wt1[n*256 + k] = (f16)W1[t]; return; }
    t -= 65536;
    if (t < 65536){ int k = t >> 8, n = t & 255; wt2[n*256 + k] = (f16)W2[t]; return; }
    t -= 65536;
    if (t < 32768){ int k = t >> 7, n = t & 127; wt3[n*256 + k] = (f16)W3[t]; return; }
    t -= 32768;
    if (t < 131072){ int k = t >> 10, n = t & 1023; wtg[n*128 + k] = (f16)Wg[t]; return; }
    t -= 131072;
    if (t < 262144){ int k = t >> 8, n = t & 255; wth1[n*1024 + k] = (f16)Wh1[t]; return; }
}

// ---------- fp16 MFMA GEMM: C[M,N] = A[M,K] @ Bt[N,K]^T ----------
// 128x128 tile, BK=32, 4 waves (2x2), each wave 64x64 via 4x4 mfma_16x16x32_f16.
// EPI: 0 = store f16 C; 1 = store f16 C + per-(row,head) att dots; 2 = head (no C store,
//      logit[row] += sum_col relu(acc+bias)*Wh2[col] via atomics).
template<int EPI, bool A_F32, bool RELU, bool HAS_BIAS>
__global__ __launch_bounds__(256,2) void gemm_f16_k(
        const void* __restrict__ Av, const f16* __restrict__ Bt,
        const float* __restrict__ bias, void* __restrict__ C,
        const float* __restrict__ att_s, const float* __restrict__ att_d,
        float* __restrict__ as_out, float* __restrict__ ad_out,
        const float* __restrict__ Wh2, float* __restrict__ logit,
        int M, int N, int K)
{
    __shared__ __align__(16) f16 As[128*32];
    __shared__ __align__(16) f16 Bs[128*32];
    __shared__ float sred[2][128][2];
    const int tid  = threadIdx.x;
    const int lane = tid & 63;
    const int wave = tid >> 6;
    const int wm = (wave >> 1) * 64, wn = (wave & 1) * 64;
    const int l15 = lane & 15, quad = lane >> 4;
    const int m0 = blockIdx.y * 128, n0 = blockIdx.x * 128;

    const int r1 = tid >> 2;
    const int ce = (tid & 3) * 8;          // element offset within 32-elem K-chunk
    const int rowA0 = m0 + r1, rowA1 = rowA0 + 64;
    const f16*  Ah = (const f16*)Av;
    const float* Af = (const float*)Av;
    const f16* B0 = Bt + (size_t)(n0 + r1) * K + ce;
    const f16* B1 = B0 + (size_t)64 * K;

    f32x4 acc[4][4] = {};
    for (int k0 = 0; k0 < K; k0 += 32){
        if (A_F32){
            f16x8v h0 = {}, h1 = {};
            if (rowA0 < M){
                float4 p = *(const float4*)(Af + (size_t)rowA0*K + k0 + ce);
                float4 q = *(const float4*)(Af + (size_t)rowA0*K + k0 + ce + 4);
                h0[0]=(f16)p.x; h0[1]=(f16)p.y; h0[2]=(f16)p.z; h0[3]=(f16)p.w;
                h0[4]=(f16)q.x; h0[5]=(f16)q.y; h0[6]=(f16)q.z; h0[7]=(f16)q.w;
            }
            if (rowA1 < M){
                float4 p = *(const float4*)(Af + (size_t)rowA1*K + k0 + ce);
                float4 q = *(const float4*)(Af + (size_t)rowA1*K + k0 + ce + 4);
                h1[0]=(f16)p.x; h1[1]=(f16)p.y; h1[2]=(f16)p.z; h1[3]=(f16)p.w;
                h1[4]=(f16)q.x; h1[5]=(f16)q.y; h1[6]=(f16)q.z; h1[7]=(f16)q.w;
            }
            *(f16x8v*)&As[tid*8]        = h0;
            *(f16x8v*)&As[tid*8 + 2048] = h1;
        } else {
            *(uint4*)&As[tid*8]        = *(const uint4*)(Ah + (size_t)rowA0*K + k0 + ce);
            *(uint4*)&As[tid*8 + 2048] = *(const uint4*)(Ah + (size_t)rowA1*K + k0 + ce);
        }
        *(uint4*)&Bs[tid*8]        = *(const uint4*)(B0 + k0);
        *(uint4*)&Bs[tid*8 + 2048] = *(const uint4*)(B1 + k0);
        __syncthreads();
        f16x8v af[4], bf[4];
        #pragma unroll
        for (int i = 0; i < 4; ++i){
            af[i] = *(const f16x8v*)&As[(wm + i*16 + l15)*32 + quad*8];
            bf[i] = *(const f16x8v*)&Bs[(wn + i*16 + l15)*32 + quad*8];
        }
        #pragma unroll
        for (int i = 0; i < 4; ++i)
            #pragma unroll
            for (int j = 0; j < 4; ++j)
                acc[i][j] = __builtin_amdgcn_mfma_f32_16x16x32_f16(af[i], bf[j], acc[i][j], 0, 0, 0);
        __syncthreads();
    }

    if (EPI == 2){
        // head: logit[row] += sum_col relu(acc + bh1[col]) * Wh2[col]
        float b4[4], w4[4];
        #pragma unroll
        for (int j = 0; j < 4; ++j){
            int cg = n0 + wn + j*16 + l15;
            b4[j] = bias[cg]; w4[j] = Wh2[cg];
        }
        #pragma unroll
        for (int i = 0; i < 4; ++i)
            #pragma unroll
            for (int r = 0; r < 4; ++r){
                float ps = 0.f;
                #pragma unroll
                for (int j = 0; j < 4; ++j){
                    float v = fmaxf(acc[i][j][r] + b4[j], 0.f);
                    ps = fmaf(v, w4[j], ps);
                }
                ps += __shfl_xor(ps, 1, 64); ps += __shfl_xor(ps, 2, 64);
                ps += __shfl_xor(ps, 4, 64); ps += __shfl_xor(ps, 8, 64);
                if (l15 == 0){
                    int row = m0 + wm + i*16 + quad*4 + r;
                    if (row < M) unsafeAtomicAdd(&logit[row], ps);
                }
            }
        return;
    }

    // store C (f16)
    #pragma unroll
    for (int i = 0; i < 4; ++i){
        int rb = m0 + wm + i*16 + quad*4;
        #pragma unroll
        for (int j = 0; j < 4; ++j){
            int col = n0 + wn + j*16 + l15;
            float bv = HAS_BIAS ? bias[col] : 0.f;
            #pragma unroll
            for (int r = 0; r < 4; ++r){
                int row = rb + r;
                if (row >= M) continue;
                float v = acc[i][j][r] + bv;
                if (RELU) v = fmaxf(v, 0.f);
                ((f16*)C)[(size_t)row*N + col] = (f16)v;
            }
        }
    }

    if (EPI == 1){
        // att dots: a_s[row,h] = sum_c acc[row,c]*att_s[h,c]  (block = one head, 128 rows)
        const int h = blockIdx.x;
        float ats[4], atd[4];
        #pragma unroll
        for (int j = 0; j < 4; ++j){
            int c = wn + j*16 + l15;
            ats[j] = att_s[h*128 + c]; atd[j] = att_d[h*128 + c];
        }
        #pragma unroll
        for (int i = 0; i < 4; ++i)
            #pragma unroll
            for (int r = 0; r < 4; ++r){
                float ps = 0.f, pd = 0.f;
                #pragma unroll
                for (int j = 0; j < 4; ++j){
                    float a = acc[i][j][r];
                    ps = fmaf(a, ats[j], ps); pd = fmaf(a, atd[j], pd);
                }
                ps += __shfl_xor(ps, 1, 64); ps += __shfl_xor(ps, 2, 64);
                ps += __shfl_xor(ps, 4, 64); ps += __shfl_xor(ps, 8, 64);
                pd += __shfl_xor(pd, 1, 64); pd += __shfl_xor(pd, 2, 64);
                pd += __shfl_xor(pd, 4, 64); pd += __shfl_xor(pd, 8, 64);
                if (l15 == 0){
                    int rl = wm + i*16 + quad*4 + r;
                    sred[0][rl][wn >> 6] = ps;
                    sred[1][rl][wn >> 6] = pd;
                }
            }
        __syncthreads();
        if (tid < 128){
            int row = m0 + tid;
            if (row < M){
                as_out[row*HEADS + h] = sred[0][tid][0] + sred[0][tid][1];
                ad_out[row*HEADS + h] = sred[1][tid][0] + sred[1][tid][1];
            }
        }
    }
}

// ---------- GCN aggregation (fp16 in/out, fp32 acc): fused self + bias + relu ----------
template<int F>   // 256 or 128
__global__ __launch_bounds__(256) void gcn_agg_f16_k(const f16* __restrict__ h, const int* __restrict__ row_off,
        const int* __restrict__ srcs, const float* __restrict__ dinv, const float* __restrict__ bias,
        f16* __restrict__ out)
{
    int wv = (blockIdx.x*256 + threadIdx.x) >> 6;
    int lane = threadIdx.x & 63;
    if (wv >= NN) return;
    float di = dinv[wv];
    int r0 = row_off[wv], r1 = row_off[wv+1];
    if (F == 256){
        f16x4v v = *(const f16x4v*)(h + (size_t)wv*256 + lane*4);
        float c = di*di;
        float a0 = (float)v[0]*c, a1 = (float)v[1]*c, a2 = (float)v[2]*c, a3 = (float)v[3]*c;
        for (int p = r0; p < r1; ++p){
            int s = srcs[p];
            float coef = dinv[s]*di;
            f16x4v u = *(const f16x4v*)(h + (size_t)s*256 + lane*4);
            a0 = fmaf((float)u[0], coef, a0); a1 = fmaf((float)u[1], coef, a1);
            a2 = fmaf((float)u[2], coef, a2); a3 = fmaf((float)u[3], coef, a3);
        }
        float4 bv = *(const float4*)(bias + lane*4);
        f16x4v o;
        o[0] = (f16)fmaxf(a0 + bv.x, 0.f); o[1] = (f16)fmaxf(a1 + bv.y, 0.f);
        o[2] = (f16)fmaxf(a2 + bv.z, 0.f); o[3] = (f16)fmaxf(a3 + bv.w, 0.f);
        *(f16x4v*)(out + (size_t)wv*256 + lane*4) = o;
    } else {
        f16x2 v = *(const f16x2*)(h + (size_t)wv*128 + lane*2);
        float c = di*di;
        float a0 = (float)v[0]*c, a1 = (float)v[1]*c;
        for (int p = r0; p < r1; ++p){
            int s = srcs[p];
            float coef = dinv[s]*di;
            f16x2 u = *(const f16x2*)(h + (size_t)s*128 + lane*2);
            a0 = fmaf((float)u[0], coef, a0); a1 = fmaf((float)u[1], coef, a1);
        }
        float2 bv = *(const float2*)(bias + lane*2);
        f16x2 o;
        o[0] = (f16)fmaxf(a0 + bv.x, 0.f); o[1] = (f16)fmaxf(a1 + bv.y, 0.f);
        *(f16x2*)(out + (size_t)wv*128 + lane*2) = o;
    }
}

// ---------- GAT softmax over CSR ----------
__global__ __launch_bounds__(256) void gat_soft_k(const int* __restrict__ row_off, const int* __restrict__ srcs,
        const float* __restrict__ a_s, const float* __restrict__ a_d,
        float* __restrict__ ex_sorted, float* __restrict__ alpha_self, float* __restrict__ inv_den)
{
    int t = blockIdx.x*256 + threadIdx.x;
    if (t >= NN*HEADS) return;
    int d = t >> 3, h = t & 7;
    float ad = a_d[t];
    float eself = lrelu(a_s[t] + ad);
    float m = eself;
    int r0 = row_off[d], r1 = row_off[d+1];
    for (int p = r0; p < r1; ++p){
        int s = srcs[p];
        m = fmaxf(m, lrelu(a_s[s*HEADS + h] + ad));
    }
    float den = expf(eself - m);
    for (int p = r0; p < r1; ++p){
        int s = srcs[p];
        float x = expf(lrelu(a_s[s*HEADS + h] + ad) - m);
        ex_sorted[(size_t)p*HEADS + h] = x;
        den += x;
    }
    float id = 1.f / den;
    alpha_self[t] = expf(eself - m) * id;
    inv_den[t]    = id;
}
// per dst node: gat[d,:] = bg + alpha_self*hg[d,:] + sum_e alpha_e*hg[src,:]   (fp16 out)
__global__ __launch_bounds__(256) void gat_out_f16_k(const f16* __restrict__ hg, const int* __restrict__ row_off,
        const int* __restrict__ srcs, const float* __restrict__ exs, const float* __restrict__ aself,
        const float* __restrict__ idn, const float* __restrict__ bg, f16* __restrict__ gat)
{
    int wv = (blockIdx.x*256 + threadIdx.x) >> 6;
    int lane = threadIdx.x & 63;
    if (wv >= NN) return;
    int hh = lane >> 3;
    float as = aself[wv*HEADS + hh];
    float id = idn[wv*HEADS + hh];
    float acc[16];
    const f16* rp = hg + (size_t)wv*GDIM + lane*16;
    f16x8v v0 = *(const f16x8v*)rp, v1 = *(const f16x8v*)(rp + 8);
    #pragma unroll
    for (int q = 0; q < 8; ++q){ acc[q] = (float)v0[q]*as; acc[8+q] = (float)v1[q]*as; }
    int r0 = row_off[wv], r1 = row_off[wv+1];
    for (int p = r0; p < r1; ++p){
        int s = srcs[p];
        float al = exs[(size_t)p*HEADS + hh] * id;
        const f16* sp = hg + (size_t)s*GDIM + lane*16;
        f16x8v u0 = *(const f16x8v*)sp, u1 = *(const f16x8v*)(sp + 8);
        #pragma unroll
        for (int q = 0; q < 8; ++q){
            acc[q]   = fmaf((float)u0[q], al, acc[q]);
            acc[8+q] = fmaf((float)u1[q], al, acc[8+q]);
        }
    }
    const float* bp = bg + lane*16;
    f16x8v o0, o1;
    #pragma unroll
    for (int q = 0; q < 8; ++q){
        o0[q] = (f16)(acc[q]   + bp[q]);
        o1[q] = (f16)(acc[8+q] + bp[8+q]);
    }
    f16* op = gat + (size_t)wv*GDIM + lane*16;
    *(f16x8v*)op = o0; *(f16x8v*)(op + 8) = o1;
}

// ---------- sigmoid of accumulated logits ----------
__global__ __launch_bounds__(256) void head_sig_k(const float* __restrict__ logit, const float* __restrict__ bh2,
                                                  float* __restrict__ w){
    int i = blockIdx.x*256 + threadIdx.x;
    if (i >= NN) return;
    w[i] = 1.f / (1.f + expf(-(logit[i] + bh2[0])));
}

// ---------- global softmax ----------
__global__ __launch_bounds__(256) void red_max_k(const float* __restrict__ w, float* __restrict__ red){
    __shared__ float s[256];
    float v = 0.f;
    for (int i = blockIdx.x*256 + threadIdx.x; i < NN; i += gridDim.x*256) v = fmaxf(v, w[i]);
    s[threadIdx.x] = v; __syncthreads();
    for (int off=128; off; off>>=1){
        if (threadIdx.x < off) s[threadIdx.x] = fmaxf(s[threadIdx.x], s[threadIdx.x+off]);
        __syncthreads();
    }
    if (!threadIdx.x) atomicMax((unsigned*)red, ordU(s[0]));
}
__global__ __launch_bounds__(256) void red_sum_k(const float* __restrict__ w, float* __restrict__ red){
    float mx = unordU(((const unsigned*)red)[0]);
    __shared__ float s[256];
    float v = 0.f;
    for (int i = blockIdx.x*256 + threadIdx.x; i < NN; i += gridDim.x*256) v += expf(w[i]-mx);
    s[threadIdx.x] = v; __syncthreads();
    for (int off=128; off; off>>=1){
        if (threadIdx.x < off) s[threadIdx.x] += s[threadIdx.x+off];
        __syncthreads();
    }
    if (!threadIdx.x) unsafeAtomicAdd(&red[1], s[0]);
}
__global__ __launch_bounds__(256) void final_k(const float* __restrict__ w, const float* __restrict__ red,
                                               float* __restrict__ out){
    int i = blockIdx.x*256 + threadIdx.x;
    if (i >= NN) return;
    float mx = unordU(((const unsigned*)red)[0]);
    out[i] = expf(w[i]-mx) / red[1];
}

// ---------- launch ----------
extern "C" void kernel_launch(void* const* d_in, const int* in_sizes, int n_in,
                              void* d_out, int out_size, void* d_ws, size_t ws_size,
                              hipStream_t stream) {
    const float* x   = (const float*)d_in[0];
    const int*   ei  = (const int*)  d_in[1];
    const float* W1  = (const float*)d_in[2];
    const float* b1  = (const float*)d_in[3];
    const float* W2  = (const float*)d_in[4];
    const float* b2  = (const float*)d_in[5];
    const float* W3  = (const float*)d_in[6];
    const float* b3  = (const float*)d_in[7];
    const float* Wg  = (const float*)d_in[8];
    const float* att_src = (const float*)d_in[9];
    const float* att_dst = (const float*)d_in[10];
    const float* bg  = (const float*)d_in[11];
    const float* Wh1 = (const float*)d_in[12];
    const float* bh1 = (const float*)d_in[13];
    const float* Wh2 = (const float*)d_in[14];
    const float* bh2 = (const float*)d_in[15];
    float* out = (float*)d_out;

    const int E = in_sizes[1] / 2;
    const int* src = ei;
    const int* dst = ei + E;

    float* ws = (float*)d_ws;
    size_t o = 0;
    auto alloc = [&](size_t nfloats){ float* p = ws + o; o += (nfloats + 3) & ~(size_t)3; return p; };
    // zero region: cnt, cursor, logit, red must stay contiguous (one memset kernel)
    int* cnt    = (int*)alloc(NN);
    int* cursor = (int*)alloc(NN);
    float* logit= alloc(NN);
    float* red  = alloc(8);
    const int ZERO_N = 3*NN + 8;

    f16* wt1   = (f16*)alloc(65536/2);
    f16* wt2   = (f16*)alloc(65536/2);
    f16* wt3   = (f16*)alloc(32768/2);
    f16* wtg   = (f16*)alloc(131072/2);
    f16* wth1  = (f16*)alloc(262144/2);
    f16* fH    = (f16*)alloc((size_t)M_PAD*256/2);
    f16* fG    = (f16*)alloc((size_t)M_PAD*256/2);
    f16* hg    = (f16*)alloc((size_t)M_PAD*GDIM/2);
    f16* gat   = (f16*)alloc((size_t)M_PAD*GDIM/2);
    float* dinv = alloc(NN);
    float* a_s  = alloc((size_t)NN*HEADS);
    float* a_d  = alloc((size_t)NN*HEADS);
    float* aself= alloc((size_t)NN*HEADS);
    float* idn  = alloc((size_t)NN*HEADS);
    float* exs  = alloc((size_t)E*HEADS);
    float* wsig = alloc(NN);
    int* row_off= (int*)alloc(NN+1);
    int* src_srt= (int*)alloc(E);

    const int nb  = (NN + 255)/256;
    const int eb  = (E + 255)/256;
    const int nwb = (NN + 3)/4;
    const dim3 blk(256);
    const int MT = M_PAD/128;   // 157

    // zero cnt/cursor/logit/red; CSR + dinv
    zero_int_k<<<(ZERO_N + 255)/256, blk, 0, stream>>>(cnt, ZERO_N);
    hist_k<<<eb, blk, 0, stream>>>(dst, cnt, E);
    scan_k<<<1, 1024, 0, stream>>>(cnt, row_off, dinv);
    scatter_k<<<eb, blk, 0, stream>>>(src, dst, row_off, cursor, src_srt, E);

    // weight transpose+convert (5 weights)
    cvt_w_k<<<(65536*2 + 32768 + 131072 + 262144)/256, blk, 0, stream>>>(
        W1, W2, W3, Wg, Wh1, wt1, wt2, wt3, wtg, wth1);

    // GCN 1: A = x (fp32, read directly)
    gemm_f16_k<0,true,false,false><<<dim3(2, MT), blk, 0, stream>>>(
        x, wt1, nullptr, fH, nullptr, nullptr, nullptr, nullptr, nullptr, nullptr, NN, 256, 256);
    gcn_agg_f16_k<256><<<nwb, blk, 0, stream>>>(fH, row_off, src_srt, dinv, b1, fG);
    // GCN 2
    gemm_f16_k<0,false,false,false><<<dim3(2, MT), blk, 0, stream>>>(
        fG, wt2, nullptr, fH, nullptr, nullptr, nullptr, nullptr, nullptr, nullptr, NN, 256, 256);
    gcn_agg_f16_k<256><<<nwb, blk, 0, stream>>>(fH, row_off, src_srt, dinv, b2, fG);
    // GCN 3 (N=128)
    gemm_f16_k<0,false,false,false><<<dim3(1, MT), blk, 0, stream>>>(
        fG, wt3, nullptr, fH, nullptr, nullptr, nullptr, nullptr, nullptr, nullptr, NN, 128, 256);
    gcn_agg_f16_k<128><<<nwb, blk, 0, stream>>>(fH, row_off, src_srt, dinv, b3, fG);

    // GAT projection (K=128, N=1024) + fused att dots
    gemm_f16_k<1,false,false,false><<<dim3(8, MT), blk, 0, stream>>>(
        fG, wtg, nullptr, hg, att_src, att_dst, a_s, a_d, nullptr, nullptr, NN, 1024, 128);
    gat_soft_k<<<(NN*HEADS)/256, blk, 0, stream>>>(row_off, src_srt, a_s, a_d, exs, aself, idn);
    gat_out_f16_k<<<nwb, blk, 0, stream>>>(hg, row_off, src_srt, exs, aself, idn, bg, gat);

    // head MLP (K=1024, N=256): fused relu(z)@Wh2 -> logit atomics (no z materialization)
    gemm_f16_k<2,false,true,true><<<dim3(2, MT), blk, 0, stream>>>(
        gat, wth1, bh1, nullptr, nullptr, nullptr, nullptr, nullptr, Wh2, logit, NN, 256, 1024);
    head_sig_k<<<nb, blk, 0, stream>>>(logit, bh2, wsig);

    // global softmax
    red_max_k<<<40, blk, 0, stream>>>(wsig, red);
    red_sum_k<<<40, blk, 0, stream>>>(wsig, red);
    final_k<<<nb, blk, 0, stream>>>(wsig, red, out);
}

// Round 5
// 381.974 us; speedup vs baseline: 28.2143x; 1.0856x over previous
//
#include <hip/hip_runtime.h>
#include <math.h>

#define NN 20000
#define HEADS 8
#define GDIM 1024
#define M_PAD 20096   // 157 * 128

typedef _Float16 f16;
typedef f16 f16x2  __attribute__((ext_vector_type(2)));
typedef f16 f16x4v __attribute__((ext_vector_type(4)));
typedef f16 f16x8v __attribute__((ext_vector_type(8)));
typedef float f32x4 __attribute__((ext_vector_type(4)));

// ---------- helpers ----------
__device__ __forceinline__ float lrelu(float x){ return x > 0.f ? x : 0.2f*x; }

// ---------- init: zero scratch ints + weight transpose/convert fp32[K][N] -> f16[N][K] ----------
__global__ __launch_bounds__(256) void init_k(int* __restrict__ zbase, int zn,
        const float* __restrict__ W1, const float* __restrict__ W2, const float* __restrict__ W3,
        const float* __restrict__ Wg, const float* __restrict__ Wh1,
        f16* __restrict__ wt1, f16* __restrict__ wt2, f16* __restrict__ wt3,
        f16* __restrict__ wtg, f16* __restrict__ wth1)
{
    int t = blockIdx.x*256 + threadIdx.x;
    if (t < zn){ zbase[t] = 0; return; }
    t -= zn;
    if (t < 65536){ int k = t >> 8, n = t & 255; wt1[n*256 + k] = (f16)W1[t]; return; }
    t -= 65536;
    if (t < 65536){ int k = t >> 8, n = t & 255; wt2[n*256 + k] = (f16)W2[t]; return; }
    t -= 65536;
    if (t < 32768){ int k = t >> 7, n = t & 127; wt3[n*256 + k] = (f16)W3[t]; return; }
    t -= 32768;
    if (t < 131072){ int k = t >> 10, n = t & 1023; wtg[n*128 + k] = (f16)Wg[t]; return; }
    t -= 131072;
    if (t < 262144){ int k = t >> 8, n = t & 255; wth1[n*1024 + k] = (f16)Wh1[t]; return; }
}

// ---------- CSR build ----------
__global__ __launch_bounds__(256) void hist_k(const int* __restrict__ dst, int* __restrict__ cnt, int E){
    int i = blockIdx.x*256 + threadIdx.x;
    if (i < E) atomicAdd(&cnt[dst[i]], 1);
}
__global__ __launch_bounds__(1024) void scan_k(const int* __restrict__ cnt, int* __restrict__ row_off,
                                               float* __restrict__ dinv){
    __shared__ int tot[1024];
    int t = threadIdx.x;
    const int CH = 20;
    int base = t*CH;
    int loc[CH]; int s = 0;
    #pragma unroll
    for (int i = 0; i < CH; ++i){
        int v = (base+i < NN) ? cnt[base+i] : 0;
        loc[i] = s; s += v;
    }
    tot[t] = s; __syncthreads();
    for (int off = 1; off < 1024; off <<= 1){
        int v = (t >= off) ? tot[t-off] : 0;
        __syncthreads();
        tot[t] += v;
        __syncthreads();
    }
    int pre = (t == 0) ? 0 : tot[t-1];
    #pragma unroll
    for (int i = 0; i < CH; ++i)
        if (base+i < NN){
            row_off[base+i] = pre + loc[i];
            dinv[base+i] = rsqrtf((float)cnt[base+i] + 1.f);
        }
    if (t == 1023) row_off[NN] = tot[1023];
}
__global__ __launch_bounds__(256) void scatter_k(const int* __restrict__ src, const int* __restrict__ dst,
        const int* __restrict__ row_off, int* __restrict__ cursor, int* __restrict__ src_sorted, int E){
    int i = blockIdx.x*256 + threadIdx.x;
    if (i >= E) return;
    int d = dst[i];
    int pos = row_off[d] + atomicAdd(&cursor[d], 1);
    src_sorted[pos] = src[i];
}

// ---------- fp16 MFMA GEMM: C[M,N] = A[M,K] @ Bt[N,K]^T ----------
// 128x128 tile, BK=32, 4 waves (2x2), each wave 64x64 via 4x4 mfma_16x16x32_f16.
// EPI: 0 = store f16 C; 1 = store f16 C + per-(row,head) att dots; 2 = head (no C store,
//      logit[row] += sum_col relu(acc+bias)*Wh2[col] via atomics).
template<int EPI, bool A_F32, bool RELU, bool HAS_BIAS>
__global__ __launch_bounds__(256,2) void gemm_f16_k(
        const void* __restrict__ Av, const f16* __restrict__ Bt,
        const float* __restrict__ bias, void* __restrict__ C,
        const float* __restrict__ att_s, const float* __restrict__ att_d,
        float* __restrict__ as_out, float* __restrict__ ad_out,
        const float* __restrict__ Wh2, float* __restrict__ logit,
        int M, int N, int K)
{
    __shared__ __align__(16) f16 As[128*32];
    __shared__ __align__(16) f16 Bs[128*32];
    __shared__ float sred[2][128][2];
    const int tid  = threadIdx.x;
    const int lane = tid & 63;
    const int wave = tid >> 6;
    const int wm = (wave >> 1) * 64, wn = (wave & 1) * 64;
    const int l15 = lane & 15, quad = lane >> 4;
    const int m0 = blockIdx.y * 128, n0 = blockIdx.x * 128;

    const int r1 = tid >> 2;
    const int ce = (tid & 3) * 8;          // element offset within 32-elem K-chunk
    const int rowA0 = m0 + r1, rowA1 = rowA0 + 64;
    const f16*  Ah = (const f16*)Av;
    const float* Af = (const float*)Av;
    const f16* B0 = Bt + (size_t)(n0 + r1) * K + ce;
    const f16* B1 = B0 + (size_t)64 * K;

    f32x4 acc[4][4] = {};
    for (int k0 = 0; k0 < K; k0 += 32){
        if (A_F32){
            f16x8v h0 = {}, h1 = {};
            if (rowA0 < M){
                float4 p = *(const float4*)(Af + (size_t)rowA0*K + k0 + ce);
                float4 q = *(const float4*)(Af + (size_t)rowA0*K + k0 + ce + 4);
                h0[0]=(f16)p.x; h0[1]=(f16)p.y; h0[2]=(f16)p.z; h0[3]=(f16)p.w;
                h0[4]=(f16)q.x; h0[5]=(f16)q.y; h0[6]=(f16)q.z; h0[7]=(f16)q.w;
            }
            if (rowA1 < M){
                float4 p = *(const float4*)(Af + (size_t)rowA1*K + k0 + ce);
                float4 q = *(const float4*)(Af + (size_t)rowA1*K + k0 + ce + 4);
                h1[0]=(f16)p.x; h1[1]=(f16)p.y; h1[2]=(f16)p.z; h1[3]=(f16)p.w;
                h1[4]=(f16)q.x; h1[5]=(f16)q.y; h1[6]=(f16)q.z; h1[7]=(f16)q.w;
            }
            *(f16x8v*)&As[tid*8]        = h0;
            *(f16x8v*)&As[tid*8 + 2048] = h1;
        } else {
            *(uint4*)&As[tid*8]        = *(const uint4*)(Ah + (size_t)rowA0*K + k0 + ce);
            *(uint4*)&As[tid*8 + 2048] = *(const uint4*)(Ah + (size_t)rowA1*K + k0 + ce);
        }
        *(uint4*)&Bs[tid*8]        = *(const uint4*)(B0 + k0);
        *(uint4*)&Bs[tid*8 + 2048] = *(const uint4*)(B1 + k0);
        __syncthreads();
        f16x8v af[4], bf[4];
        #pragma unroll
        for (int i = 0; i < 4; ++i){
            af[i] = *(const f16x8v*)&As[(wm + i*16 + l15)*32 + quad*8];
            bf[i] = *(const f16x8v*)&Bs[(wn + i*16 + l15)*32 + quad*8];
        }
        #pragma unroll
        for (int i = 0; i < 4; ++i)
            #pragma unroll
            for (int j = 0; j < 4; ++j)
                acc[i][j] = __builtin_amdgcn_mfma_f32_16x16x32_f16(af[i], bf[j], acc[i][j], 0, 0, 0);
        __syncthreads();
    }

    if (EPI == 2){
        float b4[4], w4[4];
        #pragma unroll
        for (int j = 0; j < 4; ++j){
            int cg = n0 + wn + j*16 + l15;
            b4[j] = bias[cg]; w4[j] = Wh2[cg];
        }
        #pragma unroll
        for (int i = 0; i < 4; ++i)
            #pragma unroll
            for (int r = 0; r < 4; ++r){
                float ps = 0.f;
                #pragma unroll
                for (int j = 0; j < 4; ++j){
                    float v = fmaxf(acc[i][j][r] + b4[j], 0.f);
                    ps = fmaf(v, w4[j], ps);
                }
                ps += __shfl_xor(ps, 1, 64); ps += __shfl_xor(ps, 2, 64);
                ps += __shfl_xor(ps, 4, 64); ps += __shfl_xor(ps, 8, 64);
                if (l15 == 0){
                    int row = m0 + wm + i*16 + quad*4 + r;
                    if (row < M) unsafeAtomicAdd(&logit[row], ps);
                }
            }
        return;
    }

    // store C (f16)
    #pragma unroll
    for (int i = 0; i < 4; ++i){
        int rb = m0 + wm + i*16 + quad*4;
        #pragma unroll
        for (int j = 0; j < 4; ++j){
            int col = n0 + wn + j*16 + l15;
            float bv = HAS_BIAS ? bias[col] : 0.f;
            #pragma unroll
            for (int r = 0; r < 4; ++r){
                int row = rb + r;
                if (row >= M) continue;
                float v = acc[i][j][r] + bv;
                if (RELU) v = fmaxf(v, 0.f);
                ((f16*)C)[(size_t)row*N + col] = (f16)v;
            }
        }
    }

    if (EPI == 1){
        const int h = blockIdx.x;
        float ats[4], atd[4];
        #pragma unroll
        for (int j = 0; j < 4; ++j){
            int c = wn + j*16 + l15;
            ats[j] = att_s[h*128 + c]; atd[j] = att_d[h*128 + c];
        }
        #pragma unroll
        for (int i = 0; i < 4; ++i)
            #pragma unroll
            for (int r = 0; r < 4; ++r){
                float ps = 0.f, pd = 0.f;
                #pragma unroll
                for (int j = 0; j < 4; ++j){
                    float a = acc[i][j][r];
                    ps = fmaf(a, ats[j], ps); pd = fmaf(a, atd[j], pd);
                }
                ps += __shfl_xor(ps, 1, 64); ps += __shfl_xor(ps, 2, 64);
                ps += __shfl_xor(ps, 4, 64); ps += __shfl_xor(ps, 8, 64);
                pd += __shfl_xor(pd, 1, 64); pd += __shfl_xor(pd, 2, 64);
                pd += __shfl_xor(pd, 4, 64); pd += __shfl_xor(pd, 8, 64);
                if (l15 == 0){
                    int rl = wm + i*16 + quad*4 + r;
                    sred[0][rl][wn >> 6] = ps;
                    sred[1][rl][wn >> 6] = pd;
                }
            }
        __syncthreads();
        if (tid < 128){
            int row = m0 + tid;
            if (row < M){
                as_out[row*HEADS + h] = sred[0][tid][0] + sred[0][tid][1];
                ad_out[row*HEADS + h] = sred[1][tid][0] + sred[1][tid][1];
            }
        }
    }
}

// ---------- GCN aggregation (fp16 in/out, fp32 acc): fused self + bias + relu, 2-edge unroll ----------
template<int F>   // 256 or 128
__global__ __launch_bounds__(256) void gcn_agg_f16_k(const f16* __restrict__ h, const int* __restrict__ row_off,
        const int* __restrict__ srcs, const float* __restrict__ dinv, const float* __restrict__ bias,
        f16* __restrict__ out)
{
    int wv = (blockIdx.x*256 + threadIdx.x) >> 6;
    int lane = threadIdx.x & 63;
    if (wv >= NN) return;
    float di = dinv[wv];
    int p = row_off[wv], r1 = row_off[wv+1];
    if (F == 256){
        f16x4v v = *(const f16x4v*)(h + (size_t)wv*256 + lane*4);
        float c = di*di;
        float a0 = (float)v[0]*c, a1 = (float)v[1]*c, a2 = (float)v[2]*c, a3 = (float)v[3]*c;
        for (; p+2 <= r1; p += 2){
            int s0 = srcs[p], s1 = srcs[p+1];
            float c0 = dinv[s0]*di, c1 = dinv[s1]*di;
            f16x4v u0 = *(const f16x4v*)(h + (size_t)s0*256 + lane*4);
            f16x4v u1 = *(const f16x4v*)(h + (size_t)s1*256 + lane*4);
            a0 = fmaf((float)u1[0], c1, fmaf((float)u0[0], c0, a0));
            a1 = fmaf((float)u1[1], c1, fmaf((float)u0[1], c0, a1));
            a2 = fmaf((float)u1[2], c1, fmaf((float)u0[2], c0, a2));
            a3 = fmaf((float)u1[3], c1, fmaf((float)u0[3], c0, a3));
        }
        if (p < r1){
            int s0 = srcs[p];
            float c0 = dinv[s0]*di;
            f16x4v u0 = *(const f16x4v*)(h + (size_t)s0*256 + lane*4);
            a0 = fmaf((float)u0[0], c0, a0); a1 = fmaf((float)u0[1], c0, a1);
            a2 = fmaf((float)u0[2], c0, a2); a3 = fmaf((float)u0[3], c0, a3);
        }
        float4 bv = *(const float4*)(bias + lane*4);
        f16x4v o;
        o[0] = (f16)fmaxf(a0 + bv.x, 0.f); o[1] = (f16)fmaxf(a1 + bv.y, 0.f);
        o[2] = (f16)fmaxf(a2 + bv.z, 0.f); o[3] = (f16)fmaxf(a3 + bv.w, 0.f);
        *(f16x4v*)(out + (size_t)wv*256 + lane*4) = o;
    } else {
        f16x2 v = *(const f16x2*)(h + (size_t)wv*128 + lane*2);
        float c = di*di;
        float a0 = (float)v[0]*c, a1 = (float)v[1]*c;
        for (; p+2 <= r1; p += 2){
            int s0 = srcs[p], s1 = srcs[p+1];
            float c0 = dinv[s0]*di, c1 = dinv[s1]*di;
            f16x2 u0 = *(const f16x2*)(h + (size_t)s0*128 + lane*2);
            f16x2 u1 = *(const f16x2*)(h + (size_t)s1*128 + lane*2);
            a0 = fmaf((float)u1[0], c1, fmaf((float)u0[0], c0, a0));
            a1 = fmaf((float)u1[1], c1, fmaf((float)u0[1], c0, a1));
        }
        if (p < r1){
            int s0 = srcs[p];
            float c0 = dinv[s0]*di;
            f16x2 u0 = *(const f16x2*)(h + (size_t)s0*128 + lane*2);
            a0 = fmaf((float)u0[0], c0, a0); a1 = fmaf((float)u0[1], c0, a1);
        }
        float2 bv = *(const float2*)(bias + lane*2);
        f16x2 o;
        o[0] = (f16)fmaxf(a0 + bv.x, 0.f); o[1] = (f16)fmaxf(a1 + bv.y, 0.f);
        *(f16x2*)(out + (size_t)wv*128 + lane*2) = o;
    }
}

// ---------- GAT softmax over CSR ----------
__global__ __launch_bounds__(256) void gat_soft_k(const int* __restrict__ row_off, const int* __restrict__ srcs,
        const float* __restrict__ a_s, const float* __restrict__ a_d,
        float* __restrict__ ex_sorted, float* __restrict__ alpha_self, float* __restrict__ inv_den)
{
    int t = blockIdx.x*256 + threadIdx.x;
    if (t >= NN*HEADS) return;
    int d = t >> 3, h = t & 7;
    float ad = a_d[t];
    float eself = lrelu(a_s[t] + ad);
    float m = eself;
    int r0 = row_off[d], r1 = row_off[d+1];
    for (int p = r0; p < r1; ++p){
        int s = srcs[p];
        m = fmaxf(m, lrelu(a_s[s*HEADS + h] + ad));
    }
    float den = expf(eself - m);
    for (int p = r0; p < r1; ++p){
        int s = srcs[p];
        float x = expf(lrelu(a_s[s*HEADS + h] + ad) - m);
        ex_sorted[(size_t)p*HEADS + h] = x;
        den += x;
    }
    float id = 1.f / den;
    alpha_self[t] = expf(eself - m) * id;
    inv_den[t]    = id;
}
// per (dst, half): gat[d, half*512 + :512] — 2 waves per node, 2-edge unroll
__global__ __launch_bounds__(256) void gat_out_f16_k(const f16* __restrict__ hg, const int* __restrict__ row_off,
        const int* __restrict__ srcs, const float* __restrict__ exs, const float* __restrict__ aself,
        const float* __restrict__ idn, const float* __restrict__ bg, f16* __restrict__ gat)
{
    int gw = (blockIdx.x*256 + threadIdx.x) >> 6;   // over 2*NN
    int lane = threadIdx.x & 63;
    int node = gw >> 1;
    if (node >= NN) return;
    int colbase = (gw & 1)*512 + lane*8;
    int hh = colbase >> 7;
    int nh = node*HEADS + hh;
    float as = aself[nh];
    float id = idn[nh];
    const f16* table = hg + colbase;
    f16x8v v = *(const f16x8v*)(table + (size_t)node*GDIM);
    float acc[8];
    #pragma unroll
    for (int q = 0; q < 8; ++q) acc[q] = (float)v[q]*as;
    int p = row_off[node], r1 = row_off[node+1];
    for (; p+2 <= r1; p += 2){
        int s0 = srcs[p], s1 = srcs[p+1];
        float al0 = exs[(size_t)p*HEADS + hh] * id;
        float al1 = exs[(size_t)(p+1)*HEADS + hh] * id;
        f16x8v u0 = *(const f16x8v*)(table + (size_t)s0*GDIM);
        f16x8v u1 = *(const f16x8v*)(table + (size_t)s1*GDIM);
        #pragma unroll
        for (int q = 0; q < 8; ++q)
            acc[q] = fmaf((float)u1[q], al1, fmaf((float)u0[q], al0, acc[q]));
    }
    if (p < r1){
        int s0 = srcs[p];
        float al0 = exs[(size_t)p*HEADS + hh] * id;
        f16x8v u0 = *(const f16x8v*)(table + (size_t)s0*GDIM);
        #pragma unroll
        for (int q = 0; q < 8; ++q) acc[q] = fmaf((float)u0[q], al0, acc[q]);
    }
    float4 b0 = *(const float4*)(bg + colbase);
    float4 b1 = *(const float4*)(bg + colbase + 4);
    f16x8v o;
    o[0]=(f16)(acc[0]+b0.x); o[1]=(f16)(acc[1]+b0.y); o[2]=(f16)(acc[2]+b0.z); o[3]=(f16)(acc[3]+b0.w);
    o[4]=(f16)(acc[4]+b1.x); o[5]=(f16)(acc[5]+b1.y); o[6]=(f16)(acc[6]+b1.z); o[7]=(f16)(acc[7]+b1.w);
    *(f16x8v*)(gat + (size_t)node*GDIM + colbase) = o;
}

// ---------- head: sigmoid + global exp-sum (no max pass needed: w in (0,1)) ----------
__global__ __launch_bounds__(256) void head_sum_k(const float* __restrict__ logit, const float* __restrict__ bh2,
                                                  float* __restrict__ w, float* __restrict__ red){
    __shared__ float sm[256];
    int i = blockIdx.x*256 + threadIdx.x;
    float v = 0.f;
    if (i < NN){
        float s = 1.f / (1.f + expf(-(logit[i] + bh2[0])));
        w[i] = s;
        v = expf(s);
    }
    sm[threadIdx.x] = v; __syncthreads();
    for (int off = 128; off; off >>= 1){
        if (threadIdx.x < off) sm[threadIdx.x] += sm[threadIdx.x+off];
        __syncthreads();
    }
    if (!threadIdx.x) unsafeAtomicAdd(&red[0], sm[0]);
}
__global__ __launch_bounds__(256) void final_k(const float* __restrict__ w, const float* __restrict__ red,
                                               float* __restrict__ out){
    int i = blockIdx.x*256 + threadIdx.x;
    if (i >= NN) return;
    out[i] = expf(w[i]) / red[0];
}

// ---------- launch ----------
extern "C" void kernel_launch(void* const* d_in, const int* in_sizes, int n_in,
                              void* d_out, int out_size, void* d_ws, size_t ws_size,
                              hipStream_t stream) {
    const float* x   = (const float*)d_in[0];
    const int*   ei  = (const int*)  d_in[1];
    const float* W1  = (const float*)d_in[2];
    const float* b1  = (const float*)d_in[3];
    const float* W2  = (const float*)d_in[4];
    const float* b2  = (const float*)d_in[5];
    const float* W3  = (const float*)d_in[6];
    const float* b3  = (const float*)d_in[7];
    const float* Wg  = (const float*)d_in[8];
    const float* att_src = (const float*)d_in[9];
    const float* att_dst = (const float*)d_in[10];
    const float* bg  = (const float*)d_in[11];
    const float* Wh1 = (const float*)d_in[12];
    const float* bh1 = (const float*)d_in[13];
    const float* Wh2 = (const float*)d_in[14];
    const float* bh2 = (const float*)d_in[15];
    float* out = (float*)d_out;

    const int E = in_sizes[1] / 2;
    const int* src = ei;
    const int* dst = ei + E;

    float* ws = (float*)d_ws;
    size_t o = 0;
    auto alloc = [&](size_t nfloats){ float* p = ws + o; o += (nfloats + 3) & ~(size_t)3; return p; };
    // zero region: cnt, cursor, logit, red contiguous
    int* cnt    = (int*)alloc(NN);
    int* cursor = (int*)alloc(NN);
    float* logit= alloc(NN);
    float* red  = alloc(8);
    const int ZERO_N = 3*NN + 8;

    f16* wt1   = (f16*)alloc(65536/2);
    f16* wt2   = (f16*)alloc(65536/2);
    f16* wt3   = (f16*)alloc(32768/2);
    f16* wtg   = (f16*)alloc(131072/2);
    f16* wth1  = (f16*)alloc(262144/2);
    f16* fH    = (f16*)alloc((size_t)M_PAD*256/2);
    f16* fG    = (f16*)alloc((size_t)M_PAD*256/2);
    f16* hg    = (f16*)alloc((size_t)M_PAD*GDIM/2);
    f16* gat   = (f16*)alloc((size_t)M_PAD*GDIM/2);
    float* dinv = alloc(NN);
    float* a_s  = alloc((size_t)NN*HEADS);
    float* a_d  = alloc((size_t)NN*HEADS);
    float* aself= alloc((size_t)NN*HEADS);
    float* idn  = alloc((size_t)NN*HEADS);
    float* exs  = alloc((size_t)E*HEADS);
    float* wsig = alloc(NN);
    int* row_off= (int*)alloc(NN+1);
    int* src_srt= (int*)alloc(E);

    const int nb  = (NN + 255)/256;
    const int eb  = (E + 255)/256;
    const int nwb = (NN + 3)/4;
    const dim3 blk(256);
    const int MT = M_PAD/128;   // 157

    // init (zero + weight cvt), CSR, dinv
    const int INIT_T = ZERO_N + 65536*2 + 32768 + 131072 + 262144;
    init_k<<<(INIT_T + 255)/256, blk, 0, stream>>>(cnt, ZERO_N, W1, W2, W3, Wg, Wh1,
                                                   wt1, wt2, wt3, wtg, wth1);
    hist_k<<<eb, blk, 0, stream>>>(dst, cnt, E);
    scan_k<<<1, 1024, 0, stream>>>(cnt, row_off, dinv);
    scatter_k<<<eb, blk, 0, stream>>>(src, dst, row_off, cursor, src_srt, E);

    // GCN 1: A = x (fp32, read directly)
    gemm_f16_k<0,true,false,false><<<dim3(2, MT), blk, 0, stream>>>(
        x, wt1, nullptr, fH, nullptr, nullptr, nullptr, nullptr, nullptr, nullptr, NN, 256, 256);
    gcn_agg_f16_k<256><<<nwb, blk, 0, stream>>>(fH, row_off, src_srt, dinv, b1, fG);
    // GCN 2
    gemm_f16_k<0,false,false,false><<<dim3(2, MT), blk, 0, stream>>>(
        fG, wt2, nullptr, fH, nullptr, nullptr, nullptr, nullptr, nullptr, nullptr, NN, 256, 256);
    gcn_agg_f16_k<256><<<nwb, blk, 0, stream>>>(fH, row_off, src_srt, dinv, b2, fG);
    // GCN 3 (N=128)
    gemm_f16_k<0,false,false,false><<<dim3(1, MT), blk, 0, stream>>>(
        fG, wt3, nullptr, fH, nullptr, nullptr, nullptr, nullptr, nullptr, nullptr, NN, 128, 256);
    gcn_agg_f16_k<128><<<nwb, blk, 0, stream>>>(fH, row_off, src_srt, dinv, b3, fG);

    // GAT projection (K=128, N=1024) + fused att dots
    gemm_f16_k<1,false,false,false><<<dim3(8, MT), blk, 0, stream>>>(
        fG, wtg, nullptr, hg, att_src, att_dst, a_s, a_d, nullptr, nullptr, NN, 1024, 128);
    gat_soft_k<<<(NN*HEADS)/256, blk, 0, stream>>>(row_off, src_srt, a_s, a_d, exs, aself, idn);
    gat_out_f16_k<<<NN/2, blk, 0, stream>>>(hg, row_off, src_srt, exs, aself, idn, bg, gat);

    // head MLP (K=1024, N=256): fused relu(z)@Wh2 -> logit atomics
    gemm_f16_k<2,false,true,true><<<dim3(2, MT), blk, 0, stream>>>(
        gat, wth1, bh1, nullptr, nullptr, nullptr, nullptr, nullptr, Wh2, logit, NN, 256, 1024);

    // sigmoid + global softmax (no max pass: w bounded in (0,1))
    head_sum_k<<<nb, blk, 0, stream>>>(logit, bh2, wsig, red);
    final_k<<<nb, blk, 0, stream>>>(wsig, red, out);
}